// Round 1
// baseline (653.010 us; speedup 1.0000x reference)
//
#include <hip/hip_runtime.h>

typedef __attribute__((ext_vector_type(4))) float f32x4;
typedef __attribute__((ext_vector_type(8))) short short8;
typedef unsigned short u16;

// ---------------- helpers ----------------
__device__ __forceinline__ u16 f2bf(float f) {
  unsigned int u = __float_as_uint(f);
  return (u16)((u + 0x7fffu + ((u >> 16) & 1u)) >> 16);  // RNE
}

__device__ __forceinline__ void gload16(const void* g, void* l) {
  __builtin_amdgcn_global_load_lds((const __attribute__((address_space(1))) void*)g,
                                   (__attribute__((address_space(3))) void*)l, 16, 0, 0);
}

// ---------------- converts ----------------
__global__ void cvt_f32_bf16(const float* __restrict__ in, u16* __restrict__ out, int n4) {
  int i = blockIdx.x * blockDim.x + threadIdx.x;
  int stride = gridDim.x * blockDim.x;
  for (; i < n4; i += stride) {
    float4 v = ((const float4*)in)[i];
    ushort4 o;
    o.x = f2bf(v.x); o.y = f2bf(v.y); o.z = f2bf(v.z); o.w = f2bf(v.w);
    ((ushort4*)out)[i] = o;
  }
}

// tgt [16384,1024] f32 -> cat[row*2048 + c] bf16 (first half of concat buffer)
__global__ void cvt_tgt_strided(const float* __restrict__ in, u16* __restrict__ cat, int n4) {
  int i = blockIdx.x * blockDim.x + threadIdx.x;
  int stride = gridDim.x * blockDim.x;
  for (; i < n4; i += stride) {
    int e = i * 4;
    int row = e >> 10;
    int c = e & 1023;
    float4 v = ((const float4*)in)[i];
    ushort4 o;
    o.x = f2bf(v.x); o.y = f2bf(v.y); o.z = f2bf(v.z); o.w = f2bf(v.w);
    *(ushort4*)(cat + (size_t)row * 2048 + c) = o;
  }
}

// ---------------- GEMM: C[M,N] = A[M,K] * W[N,K]^T (+bias[n]) (*rowmask[m]) ----------------
// M=16384 assumed multiple of 128; N multiple of 128; K multiple of 32.
template <bool MASK, bool OUTBF>
__global__ __launch_bounds__(256) void gemm_bt(const u16* __restrict__ A, int lda,
                                               const u16* __restrict__ W,
                                               const float* __restrict__ bias,
                                               const float* __restrict__ rowmask,
                                               void* __restrict__ Cout, int ldc,
                                               int N, int K) {
  constexpr int BK = 32;
  __shared__ u16 As[128 * BK];  // [128][32] linear (global_load_lds dest)
  __shared__ u16 Bs[128 * BK];
  const int tid = threadIdx.x;
  const int lane = tid & 63;
  const int wid = tid >> 6;
  const int lr = lane & 15, lh = lane >> 4;
  const int nbn = N >> 7;
  const int bm = blockIdx.x / nbn;
  const int bn = blockIdx.x - bm * nbn;
  const int wm = (wid >> 1) * 64;
  const int wn = (wid & 1) * 64;

  f32x4 acc[4][4];
#pragma unroll
  for (int m = 0; m < 4; ++m)
#pragma unroll
    for (int n = 0; n < 4; ++n) acc[m][n] = (f32x4){0.f, 0.f, 0.f, 0.f};

  const u16* Ab = A + (size_t)bm * 128 * lda;
  const u16* Wb = W + (size_t)bn * 128 * K;

  for (int k0 = 0; k0 < K; k0 += BK) {
    __syncthreads();  // protect LDS reuse from previous iteration
#pragma unroll
    for (int r = 0; r < 2; ++r) {
      int o = (r * 256 + tid) * 16;  // byte offset within 8KB tile
      int row = o >> 6;              // 64 bytes per row (32 bf16)
      int colb = o & 63;
      gload16((const char*)(Ab + (size_t)row * lda + k0) + colb, (char*)As + o);
      gload16((const char*)(Wb + (size_t)row * K + k0) + colb, (char*)Bs + o);
    }
    __syncthreads();  // drains vmcnt (global_load_lds) per compiler barrier semantics

    short8 af[4], bf[4];
#pragma unroll
    for (int m = 0; m < 4; ++m)
      af[m] = *(const short8*)(As + (wm + m * 16 + lr) * BK + lh * 8);
#pragma unroll
    for (int n = 0; n < 4; ++n)
      bf[n] = *(const short8*)(Bs + (wn + n * 16 + lr) * BK + lh * 8);
#pragma unroll
    for (int m = 0; m < 4; ++m)
#pragma unroll
      for (int n = 0; n < 4; ++n)
        acc[m][n] = __builtin_amdgcn_mfma_f32_16x16x32_bf16(af[m], bf[n], acc[m][n], 0, 0, 0);
  }

  // epilogue: C/D layout col=lane&15, row=(lane>>4)*4+reg
  const int r0 = bm * 128 + wm + lh * 4;
  const int c0 = bn * 128 + wn + lr;
#pragma unroll
  for (int n = 0; n < 4; ++n) {
    float bv = bias[c0 + n * 16];
#pragma unroll
    for (int m = 0; m < 4; ++m) {
#pragma unroll
      for (int i = 0; i < 4; ++i) {
        int row = r0 + m * 16 + i;
        float v = acc[m][n][i] + bv;
        if constexpr (MASK) v *= rowmask[row];
        if constexpr (OUTBF)
          ((u16*)Cout)[(size_t)row * ldc + c0 + n * 16] = f2bf(v);
        else
          ((float*)Cout)[(size_t)row * ldc + c0 + n * 16] = v;
      }
    }
  }
}

// ---------------- flash attention ----------------
// grid: B*H*(T/64) = 2048 blocks, 256 threads (4 waves x 16 q-rows).
// q   [B*T,1024] bf16 (already tgt_mask-scaled)
// kv  [B*S,2048] bf16 (already src_mask-scaled; cols 0..1023 = K, 1024.. = V)
// writes upd into cat[row][1024 + h*128 + d]
__global__ __launch_bounds__(256) void attn_fwd(const u16* __restrict__ q,
                                                const u16* __restrict__ kv,
                                                const float* __restrict__ smask,
                                                u16* __restrict__ cat) {
  __shared__ u16 Ks[64][136];      // K rows, padded (16B-aligned rows, 2-way banks)
  __shared__ u16 Vt[128][72];      // V transposed [d][s], padded
  __shared__ u16 Ps[4][16][72];    // per-wave P tile [t][s]
  const int tid = threadIdx.x;
  const int lane = tid & 63;
  const int w = tid >> 6;
  const int lr = lane & 15, lh = lane >> 4;
  const int bid = blockIdx.x;
  const int qb = bid & 7;
  const int h = (bid >> 3) & 7;
  const int b = bid >> 6;
  const int t0 = qb * 64 + w * 16;
  const float SCALE = 0.08838834764831845f;  // 1/sqrt(128)

  // Q fragments for this wave's 16 rows: A-frag row=lane&15, k=(lane>>4)*8+j
  short8 qf[4];
  {
    const u16* qp = q + (size_t)(b * 512 + t0 + lr) * 1024 + h * 128 + lh * 8;
#pragma unroll
    for (int kc = 0; kc < 4; ++kc) qf[kc] = *(const short8*)(qp + kc * 32);
  }

  f32x4 o[8];
#pragma unroll
  for (int dt = 0; dt < 8; ++dt) o[dt] = (f32x4){0.f, 0.f, 0.f, 0.f};
  float m_run[4], l_run[4];
#pragma unroll
  for (int i = 0; i < 4; ++i) { m_run[i] = -1e30f; l_run[i] = 0.f; }

  for (int s0 = 0; s0 < 512; s0 += 64) {
    __syncthreads();
    // stage K rows and transposed V
#pragma unroll
    for (int it = 0; it < 4; ++it) {
      int idx = it * 256 + tid;
      int srow = idx >> 4;
      int d0 = (idx & 15) * 8;
      const u16* kvp = kv + (size_t)(b * 512 + s0 + srow) * 2048 + h * 128;
      short8 kk = *(const short8*)(kvp + d0);
      *(short8*)(&Ks[srow][d0]) = kk;
      short8 vv = *(const short8*)(kvp + 1024 + d0);
#pragma unroll
      for (int e = 0; e < 8; ++e) Vt[d0 + e][srow] = (u16)vv[e];
    }
    __syncthreads();

    // QK^T: scores tile [16 t][64 s], C layout col(s)=lane&15, row(t)=(lane>>4)*4+i
    f32x4 sc[4];
#pragma unroll
    for (int st = 0; st < 4; ++st) {
      f32x4 c = (f32x4){0.f, 0.f, 0.f, 0.f};
#pragma unroll
      for (int kc = 0; kc < 4; ++kc) {
        short8 kb = *(const short8*)(&Ks[st * 16 + lr][kc * 32 + lh * 8]);
        c = __builtin_amdgcn_mfma_f32_16x16x32_bf16(qf[kc], kb, c, 0, 0, 0);
      }
      sc[st] = c;
    }

    float cm[4];
#pragma unroll
    for (int st = 0; st < 4; ++st) cm[st] = smask[b * 512 + s0 + st * 16 + lr];

    float pv[4][4], mx[4];
#pragma unroll
    for (int i = 0; i < 4; ++i) mx[i] = -1e30f;
#pragma unroll
    for (int st = 0; st < 4; ++st)
#pragma unroll
      for (int i = 0; i < 4; ++i) {
        float v = (cm[st] != 0.f) ? sc[st][i] * SCALE : -1e30f;
        pv[st][i] = v;
        mx[i] = fmaxf(mx[i], v);
      }
    // row-max across the 16 lanes holding this row's columns
#pragma unroll
    for (int off = 1; off < 16; off <<= 1)
#pragma unroll
      for (int i = 0; i < 4; ++i) mx[i] = fmaxf(mx[i], __shfl_xor(mx[i], off));

    float m_new[4], scl[4], rs[4];
#pragma unroll
    for (int i = 0; i < 4; ++i) {
      m_new[i] = fmaxf(m_run[i], mx[i]);
      scl[i] = __expf(m_run[i] - m_new[i]);  // both -1e30 -> exp(0)=1, harmless (l=0,O=0)
      rs[i] = 0.f;
    }
#pragma unroll
    for (int st = 0; st < 4; ++st)
#pragma unroll
      for (int i = 0; i < 4; ++i) {
        float p = (cm[st] != 0.f) ? __expf(pv[st][i] - m_new[i]) : 0.f;
        pv[st][i] = p;
        rs[i] += p;
      }
#pragma unroll
    for (int off = 1; off < 16; off <<= 1)
#pragma unroll
      for (int i = 0; i < 4; ++i) rs[i] += __shfl_xor(rs[i], off);
#pragma unroll
    for (int i = 0; i < 4; ++i) {
      l_run[i] = l_run[i] * scl[i] + rs[i];
      m_run[i] = m_new[i];
    }
#pragma unroll
    for (int dt = 0; dt < 8; ++dt)
#pragma unroll
      for (int i = 0; i < 4; ++i) o[dt][i] *= scl[i];

    // P -> per-wave LDS (transpose from C-layout to A-frag layout), wave-local
#pragma unroll
    for (int st = 0; st < 4; ++st)
#pragma unroll
      for (int i = 0; i < 4; ++i) Ps[w][lh * 4 + i][st * 16 + lr] = f2bf(pv[st][i]);

    short8 pa[2];
#pragma unroll
    for (int s2 = 0; s2 < 2; ++s2)
      pa[s2] = *(const short8*)(&Ps[w][lr][s2 * 32 + lh * 8]);
#pragma unroll
    for (int dt = 0; dt < 8; ++dt)
#pragma unroll
      for (int s2 = 0; s2 < 2; ++s2) {
        short8 vb = *(const short8*)(&Vt[dt * 16 + lr][s2 * 32 + lh * 8]);
        o[dt] = __builtin_amdgcn_mfma_f32_16x16x32_bf16(pa[s2], vb, o[dt], 0, 0, 0);
      }
  }

  float inv[4];
#pragma unroll
  for (int i = 0; i < 4; ++i) inv[i] = 1.f / l_run[i];
  u16* outp = cat + (size_t)(b * 512 + t0 + lh * 4) * 2048 + 1024 + h * 128 + lr;
#pragma unroll
  for (int dt = 0; dt < 8; ++dt)
#pragma unroll
    for (int i = 0; i < 4; ++i)
      outp[(size_t)i * 2048 + dt * 16] = f2bf(o[dt][i] * inv[i]);
}

// ---------------- launcher ----------------
extern "C" void kernel_launch(void* const* d_in, const int* in_sizes, int n_in,
                              void* d_out, int out_size, void* d_ws, size_t ws_size,
                              hipStream_t stream) {
  (void)in_sizes; (void)n_in; (void)out_size; (void)ws_size;
  const float* src      = (const float*)d_in[0];
  const float* tgt      = (const float*)d_in[1];
  const float* src_mask = (const float*)d_in[2];
  const float* tgt_mask = (const float*)d_in[3];
  const float* W_src    = (const float*)d_in[4];
  const float* b_src    = (const float*)d_in[5];
  const float* W_tgt    = (const float*)d_in[6];
  const float* b_tgt    = (const float*)d_in[7];
  const float* W_out    = (const float*)d_in[8];
  const float* b_out    = (const float*)d_in[9];

  // workspace layout (bytes); catb doubles as src_bf16 (disjoint lifetimes)
  char* ws = (char*)d_ws;
  u16* catb = (u16*)(ws);                 // [16384,2048]  67108864 B  (src_bf16, then concat[tgt|upd])
  u16* kvb  = (u16*)(ws + 67108864);      // [16384,2048]  67108864 B
  u16* qbuf = (u16*)(ws + 134217728);     // [16384,1024]  33554432 B
  u16* wsrc = (u16*)(ws + 167772160);     // [2048,2048]    8388608 B
  u16* wtgt = (u16*)(ws + 176160768);     // [1024,1024]    2097152 B
  u16* wout = (u16*)(ws + 178257920);     // [1024,2048]    4194304 B
  // total 182452224 B (~174 MiB)

  // 1) converts needed before GEMM1
  cvt_f32_bf16<<<2048, 256, 0, stream>>>(src, catb, 16384 * 2048 / 4);
  cvt_f32_bf16<<<1024, 256, 0, stream>>>(W_src, wsrc, 2048 * 2048 / 4);
  cvt_f32_bf16<<<256, 256, 0, stream>>>(W_tgt, wtgt, 1024 * 1024 / 4);
  cvt_f32_bf16<<<512, 256, 0, stream>>>(W_out, wout, 1024 * 2048 / 4);

  // 2) GEMM1: src_trans = src @ W_src^T (+b_src) * src_mask  -> kv  [16384,2048]
  gemm_bt<true, true><<<128 * 16, 256, 0, stream>>>(catb, 2048, wsrc, b_src, src_mask,
                                                    kvb, 2048, 2048, 2048);

  // 3) tgt -> bf16 into concat buffer first half (src_bf16 now dead)
  cvt_tgt_strided<<<1024, 256, 0, stream>>>(tgt, catb, 16384 * 1024 / 4);

  // 4) GEMM2: q = tgt @ W_tgt^T (+b_tgt) * tgt_mask -> qbuf [16384,1024]
  gemm_bt<true, true><<<128 * 8, 256, 0, stream>>>(catb, 2048, wtgt, b_tgt, tgt_mask,
                                                   qbuf, 1024, 1024, 1024);

  // 5) attention -> writes upd half of concat buffer
  attn_fwd<<<2048, 256, 0, stream>>>(qbuf, kvb, src_mask, catb);

  // 6) GEMM3: out = concat[tgt|upd] @ W_out^T (+b_out) -> d_out fp32 [16384,1024]
  gemm_bt<false, false><<<128 * 8, 256, 0, stream>>>(catb, 2048, wout, b_out, nullptr,
                                                     (float*)d_out, 1024, 1024, 2048);
}

// Round 2
// 508.750 us; speedup vs baseline: 1.2836x; 1.2836x over previous
//
#include <hip/hip_runtime.h>

typedef __attribute__((ext_vector_type(4))) float f32x4;
typedef __attribute__((ext_vector_type(8))) short short8;
typedef unsigned short u16;

// ---------------- helpers ----------------
__device__ __forceinline__ u16 f2bf(float f) {
  unsigned int u = __float_as_uint(f);
  return (u16)((u + 0x7fffu + ((u >> 16) & 1u)) >> 16);  // RNE
}

__device__ __forceinline__ void gload16(const void* g, void* l) {
  __builtin_amdgcn_global_load_lds((const __attribute__((address_space(1))) void*)g,
                                   (__attribute__((address_space(3))) void*)l, 16, 0, 0);
}

// ---------------- converts ----------------
__global__ void cvt_f32_bf16(const float* __restrict__ in, u16* __restrict__ out, int n4) {
  int i = blockIdx.x * blockDim.x + threadIdx.x;
  int stride = gridDim.x * blockDim.x;
  for (; i < n4; i += stride) {
    float4 v = ((const float4*)in)[i];
    ushort4 o;
    o.x = f2bf(v.x); o.y = f2bf(v.y); o.z = f2bf(v.z); o.w = f2bf(v.w);
    ((ushort4*)out)[i] = o;
  }
}

// tgt [16384,1024] f32 -> cat[row*2048 + c] bf16 (first half of concat buffer)
__global__ void cvt_tgt_strided(const float* __restrict__ in, u16* __restrict__ cat, int n4) {
  int i = blockIdx.x * blockDim.x + threadIdx.x;
  int stride = gridDim.x * blockDim.x;
  for (; i < n4; i += stride) {
    int e = i * 4;
    int row = e >> 10;
    int c = e & 1023;
    float4 v = ((const float4*)in)[i];
    ushort4 o;
    o.x = f2bf(v.x); o.y = f2bf(v.y); o.z = f2bf(v.z); o.w = f2bf(v.w);
    *(ushort4*)(cat + (size_t)row * 2048 + c) = o;
  }
}

// ---------------- GEMM 256x256, BK=32, 8 waves, 3-buffer pipelined ----------------
// C[M,N] = A[M,K] * W[N,K]^T (+bias[n]) (*rowmask[m])
// grid = (M/256)*(N/256) blocks of 512 threads. nwg must be divisible by 8.
// LDS swizzle: within each 64B row, 16B slot ^= ((row>>1)&3)  (involution; applied
// to pre-swizzled global source for global_load_lds AND to fragment ds_reads).
template <bool MASK, bool OUTBF>
__global__ __launch_bounds__(512, 2) void gemm256(const u16* __restrict__ A, int lda,
                                                  const u16* __restrict__ W,
                                                  const float* __restrict__ bias,
                                                  const float* __restrict__ rowmask,
                                                  void* __restrict__ Cout, int ldc,
                                                  int nbn, int K) {
  // 3 buffers x (A 16KB + B 16KB) = 96KB
  __shared__ __align__(16) u16 lds[3 * 16384];
  const int tid = threadIdx.x;
  const int lane = tid & 63;
  const int wid = tid >> 6;  // 0..7
  const int lr = lane & 15, lh = lane >> 4;
  const int wm = wid >> 2;   // 0..1
  const int wn = wid & 3;    // 0..3

  // XCD-aware block swizzle (nwg % 8 == 0 for all our shapes)
  const int nwg = gridDim.x;
  const int cpx = nwg >> 3;
  const int bid = (blockIdx.x & 7) * cpx + (blockIdx.x >> 3);
  const int bm = bid / nbn;
  const int bn = bid - bm * nbn;

  const u16* Ab = A + (size_t)(bm * 256) * lda;
  const u16* Wb = W + (size_t)(bn * 256) * K;

  // staging: per thread 2 chunks per half (A or B): LDS o = (r*512+tid)*16 (linear,
  // wave-uniform base + lane*16 as global_load_lds requires); source pre-swizzled.
  const char* gA[2];
  const char* gB[2];
  int ldst[2];
#pragma unroll
  for (int r = 0; r < 2; ++r) {
    int row = r * 128 + (tid >> 2);
    int cb = ((tid & 3) << 4) ^ (((row >> 1) & 3) << 4);
    gA[r] = (const char*)(Ab + (size_t)row * lda) + cb;
    gB[r] = (const char*)(Wb + (size_t)row * K) + cb;
    ldst[r] = r * 8192 + tid * 16;
  }

  auto stageA = [&](int t, int buf) {
    char* d = (char*)lds + buf * 32768;
#pragma unroll
    for (int r = 0; r < 2; ++r) gload16(gA[r] + (size_t)t * 64, d + ldst[r]);
  };
  auto stageB = [&](int t, int buf) {
    char* d = (char*)lds + buf * 32768 + 16384;
#pragma unroll
    for (int r = 0; r < 2; ++r) gload16(gB[r] + (size_t)t * 64, d + ldst[r]);
  };

  // fragment read offsets (swizzled); row = base + lr, k-slot = lh
  const int swz = ((lr >> 1) & 3) << 4;
  const int aoff = (wm * 128 + lr) * 64 + ((lh << 4) ^ swz);
  const int boff = (wn * 64 + lr) * 64 + ((lh << 4) ^ swz);

  f32x4 acc[8][4];
#pragma unroll
  for (int m = 0; m < 8; ++m)
#pragma unroll
    for (int n = 0; n < 4; ++n) acc[m][n] = (f32x4){0.f, 0.f, 0.f, 0.f};

  const int NT = K >> 5;

  // prologue: stage tiles 0 and 1; wait for tile 0 (4 newest may stay in flight)
  stageA(0, 0); stageB(0, 0);
  stageA(1, 1); stageB(1, 1);
  asm volatile("s_waitcnt vmcnt(4)" ::: "memory");
  __builtin_amdgcn_s_barrier();

  int cur = 0;
  for (int t = 0; t < NT; ++t) {
    const char* Al = (const char*)lds + cur * 32768;
    const char* Bl = Al + 16384;
    int nxt = cur + 2; if (nxt >= 3) nxt -= 3;
    const bool pf = (t + 2 < NT);

    // ---- phase A: B frags + A(m0-3); stage A-half of tile t+2 ----
    short8 bf[4], af[4];
#pragma unroll
    for (int n = 0; n < 4; ++n) bf[n] = *(const short8*)(Bl + boff + n * 1024);
#pragma unroll
    for (int m = 0; m < 4; ++m) af[m] = *(const short8*)(Al + aoff + m * 1024);
    if (pf) stageA(t + 2, nxt);
    __builtin_amdgcn_s_barrier();
    asm volatile("s_waitcnt lgkmcnt(0)" ::: "memory");
    __builtin_amdgcn_sched_barrier(0);
    __builtin_amdgcn_s_setprio(1);
#pragma unroll
    for (int m = 0; m < 4; ++m)
#pragma unroll
      for (int n = 0; n < 4; ++n)
        acc[m][n] = __builtin_amdgcn_mfma_f32_16x16x32_bf16(af[m], bf[n], acc[m][n], 0, 0, 0);
    __builtin_amdgcn_s_setprio(0);
    __builtin_amdgcn_s_barrier();

    // ---- phase B: A(m4-7); stage B-half of tile t+2; counted vmcnt ----
    short8 af2[4];
#pragma unroll
    for (int m = 0; m < 4; ++m) af2[m] = *(const short8*)(Al + aoff + 4096 + m * 1024);
    if (pf) stageB(t + 2, nxt);
    __builtin_amdgcn_s_barrier();
    asm volatile("s_waitcnt lgkmcnt(0)" ::: "memory");
    __builtin_amdgcn_sched_barrier(0);
    __builtin_amdgcn_s_setprio(1);
#pragma unroll
    for (int m = 0; m < 4; ++m)
#pragma unroll
      for (int n = 0; n < 4; ++n)
        acc[m + 4][n] = __builtin_amdgcn_mfma_f32_16x16x32_bf16(af2[m], bf[n], acc[m + 4][n], 0, 0, 0);
    __builtin_amdgcn_s_setprio(0);
    if (pf) { asm volatile("s_waitcnt vmcnt(4)" ::: "memory"); }
    else    { asm volatile("s_waitcnt vmcnt(0)" ::: "memory"); }
    __builtin_amdgcn_s_barrier();

    cur = cur + 1; if (cur >= 3) cur = 0;
  }

  // ---- epilogue ----
  const int r0 = bm * 256 + wm * 128 + lh * 4;
  const int c0 = bn * 256 + wn * 64 + lr;
  float bv[4];
#pragma unroll
  for (int n = 0; n < 4; ++n) bv[n] = bias[c0 + n * 16];
#pragma unroll
  for (int m = 0; m < 8; ++m) {
#pragma unroll
    for (int i = 0; i < 4; ++i) {
      const int row = r0 + m * 16 + i;
      float msk = 1.f;
      if constexpr (MASK) msk = rowmask[row];
#pragma unroll
      for (int n = 0; n < 4; ++n) {
        float v = (acc[m][n][i] + bv[n]) * msk;
        if constexpr (OUTBF)
          ((u16*)Cout)[(size_t)row * ldc + c0 + n * 16] = f2bf(v);
        else
          ((float*)Cout)[(size_t)row * ldc + c0 + n * 16] = v;
      }
    }
  }
}

// ---------------- flash attention (unchanged from passing round) ----------------
__global__ __launch_bounds__(256) void attn_fwd(const u16* __restrict__ q,
                                                const u16* __restrict__ kv,
                                                const float* __restrict__ smask,
                                                u16* __restrict__ cat) {
  __shared__ u16 Ks[64][136];
  __shared__ u16 Vt[128][72];
  __shared__ u16 Ps[4][16][72];
  const int tid = threadIdx.x;
  const int lane = tid & 63;
  const int w = tid >> 6;
  const int lr = lane & 15, lh = lane >> 4;
  const int bid = blockIdx.x;
  const int qb = bid & 7;
  const int h = (bid >> 3) & 7;
  const int b = bid >> 6;
  const int t0 = qb * 64 + w * 16;
  const float SCALE = 0.08838834764831845f;

  short8 qf[4];
  {
    const u16* qp = q + (size_t)(b * 512 + t0 + lr) * 1024 + h * 128 + lh * 8;
#pragma unroll
    for (int kc = 0; kc < 4; ++kc) qf[kc] = *(const short8*)(qp + kc * 32);
  }

  f32x4 o[8];
#pragma unroll
  for (int dt = 0; dt < 8; ++dt) o[dt] = (f32x4){0.f, 0.f, 0.f, 0.f};
  float m_run[4], l_run[4];
#pragma unroll
  for (int i = 0; i < 4; ++i) { m_run[i] = -1e30f; l_run[i] = 0.f; }

  for (int s0 = 0; s0 < 512; s0 += 64) {
    __syncthreads();
#pragma unroll
    for (int it = 0; it < 4; ++it) {
      int idx = it * 256 + tid;
      int srow = idx >> 4;
      int d0 = (idx & 15) * 8;
      const u16* kvp = kv + (size_t)(b * 512 + s0 + srow) * 2048 + h * 128;
      short8 kk = *(const short8*)(kvp + d0);
      *(short8*)(&Ks[srow][d0]) = kk;
      short8 vv = *(const short8*)(kvp + 1024 + d0);
#pragma unroll
      for (int e = 0; e < 8; ++e) Vt[d0 + e][srow] = (u16)vv[e];
    }
    __syncthreads();

    f32x4 sc[4];
#pragma unroll
    for (int st = 0; st < 4; ++st) {
      f32x4 c = (f32x4){0.f, 0.f, 0.f, 0.f};
#pragma unroll
      for (int kc = 0; kc < 4; ++kc) {
        short8 kb = *(const short8*)(&Ks[st * 16 + lr][kc * 32 + lh * 8]);
        c = __builtin_amdgcn_mfma_f32_16x16x32_bf16(qf[kc], kb, c, 0, 0, 0);
      }
      sc[st] = c;
    }

    float cm[4];
#pragma unroll
    for (int st = 0; st < 4; ++st) cm[st] = smask[b * 512 + s0 + st * 16 + lr];

    float pv[4][4], mx[4];
#pragma unroll
    for (int i = 0; i < 4; ++i) mx[i] = -1e30f;
#pragma unroll
    for (int st = 0; st < 4; ++st)
#pragma unroll
      for (int i = 0; i < 4; ++i) {
        float v = (cm[st] != 0.f) ? sc[st][i] * SCALE : -1e30f;
        pv[st][i] = v;
        mx[i] = fmaxf(mx[i], v);
      }
#pragma unroll
    for (int off = 1; off < 16; off <<= 1)
#pragma unroll
      for (int i = 0; i < 4; ++i) mx[i] = fmaxf(mx[i], __shfl_xor(mx[i], off));

    float m_new[4], scl[4], rs[4];
#pragma unroll
    for (int i = 0; i < 4; ++i) {
      m_new[i] = fmaxf(m_run[i], mx[i]);
      scl[i] = __expf(m_run[i] - m_new[i]);
      rs[i] = 0.f;
    }
#pragma unroll
    for (int st = 0; st < 4; ++st)
#pragma unroll
      for (int i = 0; i < 4; ++i) {
        float p = (cm[st] != 0.f) ? __expf(pv[st][i] - m_new[i]) : 0.f;
        pv[st][i] = p;
        rs[i] += p;
      }
#pragma unroll
    for (int off = 1; off < 16; off <<= 1)
#pragma unroll
      for (int i = 0; i < 4; ++i) rs[i] += __shfl_xor(rs[i], off);
#pragma unroll
    for (int i = 0; i < 4; ++i) {
      l_run[i] = l_run[i] * scl[i] + rs[i];
      m_run[i] = m_new[i];
    }
#pragma unroll
    for (int dt = 0; dt < 8; ++dt)
#pragma unroll
      for (int i = 0; i < 4; ++i) o[dt][i] *= scl[i];

#pragma unroll
    for (int st = 0; st < 4; ++st)
#pragma unroll
      for (int i = 0; i < 4; ++i) Ps[w][lh * 4 + i][st * 16 + lr] = f2bf(pv[st][i]);

    short8 pa[2];
#pragma unroll
    for (int s2 = 0; s2 < 2; ++s2)
      pa[s2] = *(const short8*)(&Ps[w][lr][s2 * 32 + lh * 8]);
#pragma unroll
    for (int dt = 0; dt < 8; ++dt)
#pragma unroll
      for (int s2 = 0; s2 < 2; ++s2) {
        short8 vb = *(const short8*)(&Vt[dt * 16 + lr][s2 * 32 + lh * 8]);
        o[dt] = __builtin_amdgcn_mfma_f32_16x16x32_bf16(pa[s2], vb, o[dt], 0, 0, 0);
      }
  }

  float inv[4];
#pragma unroll
  for (int i = 0; i < 4; ++i) inv[i] = 1.f / l_run[i];
  u16* outp = cat + (size_t)(b * 512 + t0 + lh * 4) * 2048 + 1024 + h * 128 + lr;
#pragma unroll
  for (int dt = 0; dt < 8; ++dt)
#pragma unroll
    for (int i = 0; i < 4; ++i)
      outp[(size_t)i * 2048 + dt * 16] = f2bf(o[dt][i] * inv[i]);
}

// ---------------- launcher ----------------
extern "C" void kernel_launch(void* const* d_in, const int* in_sizes, int n_in,
                              void* d_out, int out_size, void* d_ws, size_t ws_size,
                              hipStream_t stream) {
  (void)in_sizes; (void)n_in; (void)out_size; (void)ws_size;
  const float* src      = (const float*)d_in[0];
  const float* tgt      = (const float*)d_in[1];
  const float* src_mask = (const float*)d_in[2];
  const float* tgt_mask = (const float*)d_in[3];
  const float* W_src    = (const float*)d_in[4];
  const float* b_src    = (const float*)d_in[5];
  const float* W_tgt    = (const float*)d_in[6];
  const float* b_tgt    = (const float*)d_in[7];
  const float* W_out    = (const float*)d_in[8];
  const float* b_out    = (const float*)d_in[9];

  char* ws = (char*)d_ws;
  u16* catb = (u16*)(ws);                 // [16384,2048] (src_bf16, then concat[tgt|upd])
  u16* kvb  = (u16*)(ws + 67108864);      // [16384,2048]
  u16* qbuf = (u16*)(ws + 134217728);     // [16384,1024]
  u16* wsrc = (u16*)(ws + 167772160);     // [2048,2048]
  u16* wtgt = (u16*)(ws + 176160768);     // [1024,1024]
  u16* wout = (u16*)(ws + 178257920);     // [1024,2048]

  cvt_f32_bf16<<<2048, 256, 0, stream>>>(src, catb, 16384 * 2048 / 4);
  cvt_f32_bf16<<<1024, 256, 0, stream>>>(W_src, wsrc, 2048 * 2048 / 4);
  cvt_f32_bf16<<<256, 256, 0, stream>>>(W_tgt, wtgt, 1024 * 1024 / 4);
  cvt_f32_bf16<<<512, 256, 0, stream>>>(W_out, wout, 1024 * 2048 / 4);

  // GEMM1: kv = (src @ W_src^T + b_src) * src_mask   [16384,2048]
  gemm256<true, true><<<512, 512, 0, stream>>>(catb, 2048, wsrc, b_src, src_mask,
                                               kvb, 2048, 8, 2048);

  // tgt -> bf16 into concat buffer first half (src_bf16 now dead)
  cvt_tgt_strided<<<1024, 256, 0, stream>>>(tgt, catb, 16384 * 1024 / 4);

  // GEMM2: q = (tgt @ W_tgt^T + b_tgt) * tgt_mask    [16384,1024]
  gemm256<true, true><<<256, 512, 0, stream>>>(catb, 2048, wtgt, b_tgt, tgt_mask,
                                               qbuf, 1024, 4, 1024);

  // attention -> writes upd half of concat buffer
  attn_fwd<<<2048, 256, 0, stream>>>(qbuf, kvb, src_mask, catb);

  // GEMM3: out = concat[tgt|upd] @ W_out^T + b_out   [16384,1024] fp32
  gemm256<false, false><<<256, 512, 0, stream>>>(catb, 2048, wout, b_out, nullptr,
                                                 (float*)d_out, 1024, 4, 2048);
}

// Round 3
// 411.917 us; speedup vs baseline: 1.5853x; 1.2351x over previous
//
#include <hip/hip_runtime.h>

typedef __attribute__((ext_vector_type(4))) float f32x4;
typedef __attribute__((ext_vector_type(8))) short short8;
typedef unsigned short u16;

// ---------------- helpers ----------------
__device__ __forceinline__ u16 f2bf(float f) {
  unsigned int u = __float_as_uint(f);
  return (u16)((u + 0x7fffu + ((u >> 16) & 1u)) >> 16);  // RNE
}

__device__ __forceinline__ void gload16(const void* g, void* l) {
  __builtin_amdgcn_global_load_lds((const __attribute__((address_space(1))) void*)g,
                                   (__attribute__((address_space(3))) void*)l, 16, 0, 0);
}

// ---------------- converts ----------------
__global__ void cvt_f32_bf16(const float* __restrict__ in, u16* __restrict__ out, int n4) {
  int i = blockIdx.x * blockDim.x + threadIdx.x;
  int stride = gridDim.x * blockDim.x;
  for (; i < n4; i += stride) {
    float4 v = ((const float4*)in)[i];
    ushort4 o;
    o.x = f2bf(v.x); o.y = f2bf(v.y); o.z = f2bf(v.z); o.w = f2bf(v.w);
    ((ushort4*)out)[i] = o;
  }
}

// tgt [16384,1024] f32 -> cat[row*2048 + c] bf16 (first half of concat buffer)
__global__ void cvt_tgt_strided(const float* __restrict__ in, u16* __restrict__ cat, int n4) {
  int i = blockIdx.x * blockDim.x + threadIdx.x;
  int stride = gridDim.x * blockDim.x;
  for (; i < n4; i += stride) {
    int e = i * 4;
    int row = e >> 10;
    int c = e & 1023;
    float4 v = ((const float4*)in)[i];
    ushort4 o;
    o.x = f2bf(v.x); o.y = f2bf(v.y); o.z = f2bf(v.z); o.w = f2bf(v.w);
    *(ushort4*)(cat + (size_t)row * 2048 + c) = o;
  }
}

// ---------------- GEMM 256x256, BK=32, 8 waves, 3-buffer pipelined ----------------
// C[M,N] = A[M,K] * W[N,K]^T (+bias[n]) (*rowmask[m])
// VSPLIT (GEMM1 only): cols <1024 -> Cout (K half, ldc); cols >=1024 -> vTout
// transposed as vT[(b*8+h)*128+d][s] (rows = b*512+s).
template <bool MASK, bool OUTBF, bool VSPLIT>
__global__ __launch_bounds__(512, 2) void gemm256(const u16* __restrict__ A, int lda,
                                                  const u16* __restrict__ W,
                                                  const float* __restrict__ bias,
                                                  const float* __restrict__ rowmask,
                                                  void* __restrict__ Cout, int ldc,
                                                  int nbn, int K,
                                                  u16* __restrict__ vTout) {
  __shared__ __align__(16) u16 lds[3 * 16384];
  const int tid = threadIdx.x;
  const int lane = tid & 63;
  const int wid = tid >> 6;
  const int lr = lane & 15, lh = lane >> 4;
  const int wm = wid >> 2;
  const int wn = wid & 3;

  const int nwg = gridDim.x;
  const int cpx = nwg >> 3;
  const int bid = (blockIdx.x & 7) * cpx + (blockIdx.x >> 3);
  const int bm = bid / nbn;
  const int bn = bid - bm * nbn;

  const u16* Ab = A + (size_t)(bm * 256) * lda;
  const u16* Wb = W + (size_t)(bn * 256) * K;

  const char* gA[2];
  const char* gB[2];
  int ldst[2];
#pragma unroll
  for (int r = 0; r < 2; ++r) {
    int row = r * 128 + (tid >> 2);
    int cb = ((tid & 3) << 4) ^ (((row >> 1) & 3) << 4);
    gA[r] = (const char*)(Ab + (size_t)row * lda) + cb;
    gB[r] = (const char*)(Wb + (size_t)row * K) + cb;
    ldst[r] = r * 8192 + tid * 16;
  }

  auto stageA = [&](int t, int buf) {
    char* d = (char*)lds + buf * 32768;
#pragma unroll
    for (int r = 0; r < 2; ++r) gload16(gA[r] + (size_t)t * 64, d + ldst[r]);
  };
  auto stageB = [&](int t, int buf) {
    char* d = (char*)lds + buf * 32768 + 16384;
#pragma unroll
    for (int r = 0; r < 2; ++r) gload16(gB[r] + (size_t)t * 64, d + ldst[r]);
  };

  const int swz = ((lr >> 1) & 3) << 4;
  const int aoff = (wm * 128 + lr) * 64 + ((lh << 4) ^ swz);
  const int boff = (wn * 64 + lr) * 64 + ((lh << 4) ^ swz);

  f32x4 acc[8][4];
#pragma unroll
  for (int m = 0; m < 8; ++m)
#pragma unroll
    for (int n = 0; n < 4; ++n) acc[m][n] = (f32x4){0.f, 0.f, 0.f, 0.f};

  const int NT = K >> 5;

  stageA(0, 0); stageB(0, 0);
  stageA(1, 1); stageB(1, 1);
  asm volatile("s_waitcnt vmcnt(4)" ::: "memory");
  __builtin_amdgcn_s_barrier();

  int cur = 0;
  for (int t = 0; t < NT; ++t) {
    const char* Al = (const char*)lds + cur * 32768;
    const char* Bl = Al + 16384;
    int nxt = cur + 2; if (nxt >= 3) nxt -= 3;
    const bool pf = (t + 2 < NT);

    short8 bf[4], af[4];
#pragma unroll
    for (int n = 0; n < 4; ++n) bf[n] = *(const short8*)(Bl + boff + n * 1024);
#pragma unroll
    for (int m = 0; m < 4; ++m) af[m] = *(const short8*)(Al + aoff + m * 1024);
    if (pf) stageA(t + 2, nxt);
    __builtin_amdgcn_s_barrier();
    asm volatile("s_waitcnt lgkmcnt(0)" ::: "memory");
    __builtin_amdgcn_sched_barrier(0);
    __builtin_amdgcn_s_setprio(1);
#pragma unroll
    for (int m = 0; m < 4; ++m)
#pragma unroll
      for (int n = 0; n < 4; ++n)
        acc[m][n] = __builtin_amdgcn_mfma_f32_16x16x32_bf16(af[m], bf[n], acc[m][n], 0, 0, 0);
    __builtin_amdgcn_s_setprio(0);
    __builtin_amdgcn_s_barrier();

    short8 af2[4];
#pragma unroll
    for (int m = 0; m < 4; ++m) af2[m] = *(const short8*)(Al + aoff + 4096 + m * 1024);
    if (pf) stageB(t + 2, nxt);
    __builtin_amdgcn_s_barrier();
    asm volatile("s_waitcnt lgkmcnt(0)" ::: "memory");
    __builtin_amdgcn_sched_barrier(0);
    __builtin_amdgcn_s_setprio(1);
#pragma unroll
    for (int m = 0; m < 4; ++m)
#pragma unroll
      for (int n = 0; n < 4; ++n)
        acc[m + 4][n] = __builtin_amdgcn_mfma_f32_16x16x32_bf16(af2[m], bf[n], acc[m + 4][n], 0, 0, 0);
    __builtin_amdgcn_s_setprio(0);
    if (pf) { asm volatile("s_waitcnt vmcnt(4)" ::: "memory"); }
    else    { asm volatile("s_waitcnt vmcnt(0)" ::: "memory"); }
    __builtin_amdgcn_s_barrier();

    cur = cur + 1; if (cur >= 3) cur = 0;
  }

  // ---- epilogue ----
  const int r0 = bm * 256 + wm * 128 + lh * 4;
  const int c0 = bn * 256 + wn * 64 + lr;
  float bv[4];
#pragma unroll
  for (int n = 0; n < 4; ++n) bv[n] = bias[c0 + n * 16];

  if constexpr (VSPLIT) {
    if (c0 >= 1024) {
      // V half -> transposed vT[(b*8+h)*128+d][s], 4 consecutive s per ushort4
      const int b = r0 >> 9;  // 128-row wave block never crosses a 512-row boundary
      u16* vrow[4];
#pragma unroll
      for (int n = 0; n < 4; ++n) {
        int vcol = c0 + n * 16 - 1024;
        vrow[n] = vTout + ((size_t)(b * 8 + (vcol >> 7)) * 128 + (vcol & 127)) * 512;
      }
#pragma unroll
      for (int m = 0; m < 8; ++m) {
        float mk[4];
#pragma unroll
        for (int i = 0; i < 4; ++i) mk[i] = rowmask[r0 + m * 16 + i];
        const int s = (r0 + m * 16) & 511;
#pragma unroll
        for (int n = 0; n < 4; ++n) {
          ushort4 o;
          o.x = f2bf((acc[m][n][0] + bv[n]) * mk[0]);
          o.y = f2bf((acc[m][n][1] + bv[n]) * mk[1]);
          o.z = f2bf((acc[m][n][2] + bv[n]) * mk[2]);
          o.w = f2bf((acc[m][n][3] + bv[n]) * mk[3]);
          *(ushort4*)(vrow[n] + s) = o;
        }
      }
      return;
    }
  }

#pragma unroll
  for (int m = 0; m < 8; ++m) {
#pragma unroll
    for (int i = 0; i < 4; ++i) {
      const int row = r0 + m * 16 + i;
      float msk = 1.f;
      if constexpr (MASK) msk = rowmask[row];
#pragma unroll
      for (int n = 0; n < 4; ++n) {
        float v = (acc[m][n][i] + bv[n]) * msk;
        if constexpr (OUTBF)
          ((u16*)Cout)[(size_t)row * ldc + c0 + n * 16] = f2bf(v);
        else
          ((float*)Cout)[(size_t)row * ldc + c0 + n * 16] = v;
      }
    }
  }
}

// ---------------- flash attention ----------------
// grid: 2048 blocks (blockIdx = qb*256 + b*8 + h, so all 8 qb of a (b,h) share an XCD),
// 256 threads (4 waves x 16 q-rows).
// q    [B*T,1024] bf16 (tgt_mask-scaled)
// kbuf [B*S,1024] bf16 K (src_mask-scaled)
// vT   [(b*8+h)*128+d][512 s] bf16 V transposed (src_mask-scaled)
// writes upd into cat[row][1024 + h*128 + d]
__global__ __launch_bounds__(256) void attn_fwd(const u16* __restrict__ q,
                                                const u16* __restrict__ kbuf,
                                                const u16* __restrict__ vT,
                                                const float* __restrict__ smask,
                                                u16* __restrict__ cat) {
  // LDS 40960 B -> 4 blocks/CU. All tiles linear + XOR-swizzled (slot ^= row&7).
  __shared__ __align__(16) u16 lds[20480];
  u16* Ks = lds;            // [64 s][128 d]   16KB, 16 slots/row
  u16* Vt = lds + 8192;     // [128 d][64 s]   16KB, 8 slots/row
  u16* Ps = lds + 16384;    // 4 waves x [16 t][64 s] swizzled, 8KB
  const int tid = threadIdx.x;
  const int lane = tid & 63;
  const int w = tid >> 6;
  const int lr = lane & 15, lh = lane >> 4;
  const int bh = blockIdx.x & 255;
  const int qb = blockIdx.x >> 8;
  const int b = bh >> 3;
  const int h = bh & 7;
  const int t0 = qb * 64 + w * 16;
  const float SCALE = 0.08838834764831845f;  // 1/sqrt(128)

  const u16* kbase = kbuf + (size_t)(b * 512) * 1024 + h * 128;
  const u16* vbase = vT + (size_t)bh * 128 * 512;

  // Q fragments: A-frag row=lane&15, k=(lane>>4)*8+j
  short8 qf[4];
  {
    const u16* qp = q + (size_t)(b * 512 + t0 + lr) * 1024 + h * 128 + lh * 8;
#pragma unroll
    for (int kc = 0; kc < 4; ++kc) qf[kc] = *(const short8*)(qp + kc * 32);
  }

  f32x4 o[8];
#pragma unroll
  for (int dt = 0; dt < 8; ++dt) o[dt] = (f32x4){0.f, 0.f, 0.f, 0.f};
  float m_run[4], l_run[4];
#pragma unroll
  for (int i = 0; i < 4; ++i) { m_run[i] = -1e30f; l_run[i] = 0.f; }

  for (int s0 = 0; s0 < 512; s0 += 64) {
    __syncthreads();
    // stage K tile and V^T tile via global_load_lds (linear dest, pre-swizzled src)
#pragma unroll
    for (int it = 0; it < 4; ++it) {
      int idx = it * 256 + tid;
      int kr = idx >> 4, ks = idx & 15;
      gload16(kbase + (size_t)(s0 + kr) * 1024 + ((ks ^ (kr & 7)) * 8), (char*)Ks + idx * 16);
      int vr = idx >> 3, vs = idx & 7;
      gload16(vbase + (size_t)vr * 512 + s0 + ((vs ^ (vr & 7)) * 8), (char*)Vt + idx * 16);
    }
    asm volatile("s_waitcnt vmcnt(0)" ::: "memory");
    __syncthreads();

    // QK^T: scores tile [16 t][64 s], C layout col(s)=lane&15, row(t)=(lane>>4)*4+i
    f32x4 sc[4];
#pragma unroll
    for (int st = 0; st < 4; ++st) {
      f32x4 c = (f32x4){0.f, 0.f, 0.f, 0.f};
      const int row = st * 16 + lr;
#pragma unroll
      for (int kc = 0; kc < 4; ++kc) {
        short8 kb = *(const short8*)((const char*)Ks + row * 256 +
                                     ((kc * 64 + lh * 16) ^ ((row & 7) << 4)));
        c = __builtin_amdgcn_mfma_f32_16x16x32_bf16(qf[kc], kb, c, 0, 0, 0);
      }
      sc[st] = c;
    }

    float cm[4];
#pragma unroll
    for (int st = 0; st < 4; ++st) cm[st] = smask[b * 512 + s0 + st * 16 + lr];

    float pv[4][4], mx[4];
#pragma unroll
    for (int i = 0; i < 4; ++i) mx[i] = -1e30f;
#pragma unroll
    for (int st = 0; st < 4; ++st)
#pragma unroll
      for (int i = 0; i < 4; ++i) {
        float v = (cm[st] != 0.f) ? sc[st][i] * SCALE : -1e30f;
        pv[st][i] = v;
        mx[i] = fmaxf(mx[i], v);
      }
#pragma unroll
    for (int off = 1; off < 16; off <<= 1)
#pragma unroll
      for (int i = 0; i < 4; ++i) mx[i] = fmaxf(mx[i], __shfl_xor(mx[i], off));

    float m_new[4], scl[4], rs[4];
#pragma unroll
    for (int i = 0; i < 4; ++i) {
      m_new[i] = fmaxf(m_run[i], mx[i]);
      scl[i] = __expf(m_run[i] - m_new[i]);
      rs[i] = 0.f;
    }
#pragma unroll
    for (int st = 0; st < 4; ++st)
#pragma unroll
      for (int i = 0; i < 4; ++i) {
        float p = (cm[st] != 0.f) ? __expf(pv[st][i] - m_new[i]) : 0.f;
        pv[st][i] = p;
        rs[i] += p;
      }
#pragma unroll
    for (int off = 1; off < 16; off <<= 1)
#pragma unroll
      for (int i = 0; i < 4; ++i) rs[i] += __shfl_xor(rs[i], off);
#pragma unroll
    for (int i = 0; i < 4; ++i) {
      l_run[i] = l_run[i] * scl[i] + rs[i];
      m_run[i] = m_new[i];
    }
#pragma unroll
    for (int dt = 0; dt < 8; ++dt)
#pragma unroll
      for (int i = 0; i < 4; ++i) o[dt][i] *= scl[i];

    // P -> per-wave swizzled LDS tile (transpose C-layout -> A-frag layout)
#pragma unroll
    for (int st = 0; st < 4; ++st)
#pragma unroll
      for (int i = 0; i < 4; ++i) {
        const int prow = lh * 4 + i;
        Ps[w * 1024 + prow * 64 + (((st * 2 + (lr >> 3)) ^ (prow & 7)) * 8) + (lr & 7)] =
            f2bf(pv[st][i]);
      }

    short8 pa[2];
#pragma unroll
    for (int s2 = 0; s2 < 2; ++s2)
      pa[s2] = *(const short8*)(Ps + w * 1024 + lr * 64 + (((s2 * 4 + lh) ^ (lr & 7)) * 8));
#pragma unroll
    for (int dt = 0; dt < 8; ++dt) {
#pragma unroll
      for (int s2 = 0; s2 < 2; ++s2) {
        const int row = dt * 16 + lr;
        short8 vb = *(const short8*)((const char*)Vt + row * 128 +
                                     ((s2 * 64 + lh * 16) ^ ((row & 7) << 4)));
        o[dt] = __builtin_amdgcn_mfma_f32_16x16x32_bf16(pa[s2], vb, o[dt], 0, 0, 0);
      }
    }
  }

  float inv[4];
#pragma unroll
  for (int i = 0; i < 4; ++i) inv[i] = 1.f / l_run[i];
  u16* outp = cat + (size_t)(b * 512 + t0 + lh * 4) * 2048 + 1024 + h * 128 + lr;
#pragma unroll
  for (int dt = 0; dt < 8; ++dt)
#pragma unroll
    for (int i = 0; i < 4; ++i)
      outp[(size_t)i * 2048 + dt * 16] = f2bf(o[dt][i] * inv[i]);
}

// ---------------- launcher ----------------
extern "C" void kernel_launch(void* const* d_in, const int* in_sizes, int n_in,
                              void* d_out, int out_size, void* d_ws, size_t ws_size,
                              hipStream_t stream) {
  (void)in_sizes; (void)n_in; (void)out_size; (void)ws_size;
  const float* src      = (const float*)d_in[0];
  const float* tgt      = (const float*)d_in[1];
  const float* src_mask = (const float*)d_in[2];
  const float* tgt_mask = (const float*)d_in[3];
  const float* W_src    = (const float*)d_in[4];
  const float* b_src    = (const float*)d_in[5];
  const float* W_tgt    = (const float*)d_in[6];
  const float* b_tgt    = (const float*)d_in[7];
  const float* W_out    = (const float*)d_in[8];
  const float* b_out    = (const float*)d_in[9];

  char* ws = (char*)d_ws;
  u16* catb = (u16*)(ws);                 // [16384,2048] (src_bf16, then concat[tgt|upd])
  u16* kbuf = (u16*)(ws + 67108864);      // [16384,1024] K
  u16* vTb  = (u16*)(ws + 100663296);     // [256*128,512] V^T
  u16* qbuf = (u16*)(ws + 134217728);     // [16384,1024] Q
  u16* wsrc = (u16*)(ws + 167772160);     // [2048,2048]
  u16* wtgt = (u16*)(ws + 176160768);     // [1024,1024]
  u16* wout = (u16*)(ws + 178257920);     // [1024,2048]

  cvt_f32_bf16<<<2048, 256, 0, stream>>>(src, catb, 16384 * 2048 / 4);
  cvt_f32_bf16<<<1024, 256, 0, stream>>>(W_src, wsrc, 2048 * 2048 / 4);
  cvt_f32_bf16<<<256, 256, 0, stream>>>(W_tgt, wtgt, 1024 * 1024 / 4);
  cvt_f32_bf16<<<512, 256, 0, stream>>>(W_out, wout, 1024 * 2048 / 4);

  // GEMM1: (src @ W_src^T + b_src) * src_mask -> K half to kbuf, V half transposed to vTb
  gemm256<true, true, true><<<512, 512, 0, stream>>>(catb, 2048, wsrc, b_src, src_mask,
                                                     kbuf, 1024, 8, 2048, vTb);

  // tgt -> bf16 into concat buffer first half (src_bf16 now dead)
  cvt_tgt_strided<<<1024, 256, 0, stream>>>(tgt, catb, 16384 * 1024 / 4);

  // GEMM2: q = (tgt @ W_tgt^T + b_tgt) * tgt_mask    [16384,1024]
  gemm256<true, true, false><<<256, 512, 0, stream>>>(catb, 2048, wtgt, b_tgt, tgt_mask,
                                                      qbuf, 1024, 4, 1024, nullptr);

  // attention -> writes upd half of concat buffer
  attn_fwd<<<2048, 256, 0, stream>>>(qbuf, kbuf, vTb, src_mask, catb);

  // GEMM3: out = concat[tgt|upd] @ W_out^T + b_out   [16384,1024] fp32
  gemm256<false, false, false><<<256, 512, 0, stream>>>(catb, 2048, wout, b_out, nullptr,
                                                        (float*)d_out, 1024, 4, 2048, nullptr);
}

// Round 4
// 392.565 us; speedup vs baseline: 1.6634x; 1.0493x over previous
//
#include <hip/hip_runtime.h>

typedef __attribute__((ext_vector_type(4))) float f32x4;
typedef __attribute__((ext_vector_type(8))) short short8;
typedef unsigned short u16;

// ---------------- helpers ----------------
__device__ __forceinline__ u16 f2bf(float f) {
  unsigned int u = __float_as_uint(f);
  return (u16)((u + 0x7fffu + ((u >> 16) & 1u)) >> 16);  // RNE
}

__device__ __forceinline__ void gload16(const void* g, void* l) {
  __builtin_amdgcn_global_load_lds((const __attribute__((address_space(1))) void*)g,
                                   (__attribute__((address_space(3))) void*)l, 16, 0, 0);
}

// ---------------- converts ----------------
__global__ void cvt_f32_bf16(const float* __restrict__ in, u16* __restrict__ out, int n4) {
  int i = blockIdx.x * blockDim.x + threadIdx.x;
  int stride = gridDim.x * blockDim.x;
  for (; i < n4; i += stride) {
    float4 v = ((const float4*)in)[i];
    ushort4 o;
    o.x = f2bf(v.x); o.y = f2bf(v.y); o.z = f2bf(v.z); o.w = f2bf(v.w);
    ((ushort4*)out)[i] = o;
  }
}

// tgt [16384,1024] f32 -> cat[row*2048 + c] bf16 (first half of concat buffer)
__global__ void cvt_tgt_strided(const float* __restrict__ in, u16* __restrict__ cat, int n4) {
  int i = blockIdx.x * blockDim.x + threadIdx.x;
  int stride = gridDim.x * blockDim.x;
  for (; i < n4; i += stride) {
    int e = i * 4;
    int row = e >> 10;
    int c = e & 1023;
    float4 v = ((const float4*)in)[i];
    ushort4 o;
    o.x = f2bf(v.x); o.y = f2bf(v.y); o.z = f2bf(v.z); o.w = f2bf(v.w);
    *(ushort4*)(cat + (size_t)row * 2048 + c) = o;
  }
}

// ---------------- GEMM 256x256, BK=64, 8 waves, 4-phase counted-vmcnt pipeline ----------
// C[M,N] = A[M,K] * W[N,K]^T (+bias[n]) (*rowmask[m])
// LDS: 2 buffers x 64KB; buffer = A[256][64] (halves A0/A1 of 128 rows) + B[256][64]
// (halves B0/B1). Rows are 128B; 16B slot swizzle: slot ^= (row&7).
// Per-wave output: rows {wm*64 + mh*128}, cols {wn*32 + nh*128} — quadrant (mh,nh)
// per phase so that phase p consumes half-tiles {p0:A0+B0, p1:B1, p2:A1, p3:-}
// uniformly across waves. Stage order per tile: A0,B0,B1,A1 (lead = 4 phases);
// uniform vmcnt(4) per phase end keeps 2 halves in flight across barriers.
template <bool MASK, bool OUTBF, bool VSPLIT>
__global__ __launch_bounds__(512) void gemm256(const u16* __restrict__ A, int lda,
                                               const u16* __restrict__ W,
                                               const float* __restrict__ bias,
                                               const float* __restrict__ rowmask,
                                               void* __restrict__ Cout, int ldc,
                                               int nbn, int K,
                                               u16* __restrict__ vTout) {
  __shared__ __align__(16) u16 lds[2 * 32768];  // 128 KiB
  const int tid = threadIdx.x;
  const int lane = tid & 63;
  const int wid = tid >> 6;
  const int lr = lane & 15, lh = lane >> 4;
  const int wm = wid >> 2;  // 0..1
  const int wn = wid & 3;   // 0..3

  // XCD-aware block swizzle (nwg % 8 == 0 for all our shapes)
  const int nwg = gridDim.x;
  const int cpx = nwg >> 3;
  const int bid = (blockIdx.x & 7) * cpx + (blockIdx.x >> 3);
  const int bm = bid / nbn;
  const int bn = bid - bm * nbn;

  // staging thread mapping: chunk i = c*512+tid; row_in_half = i>>3, slot = i&7,
  // source col16 = slot ^ (row&7). (row+64)&7 == row&7, so scol shared by both chunks.
  const int srow = tid >> 3;
  const int scol = ((tid & 7) ^ (srow & 7)) << 3;
  const u16* As0 = A + (size_t)(bm * 256 + srow) * lda + scol;
  const u16* Ws0 = W + (size_t)(bn * 256 + srow) * K + scol;

  auto stageA = [&](int h, int t, int buf) {
    char* d = (char*)lds + buf * 65536 + h * 16384 + tid * 16;
    const u16* s = As0 + (size_t)(h * 128) * lda + t * 64;
    gload16(s, d);
    gload16(s + (size_t)64 * lda, d + 8192);
  };
  auto stageB = [&](int h, int t, int buf) {
    char* d = (char*)lds + buf * 65536 + 32768 + h * 16384 + tid * 16;
    const u16* s = Ws0 + (size_t)(h * 128) * K + t * 64;
    gload16(s, d);
    gload16(s + (size_t)64 * K, d + 8192);
  };

  // fragment read constants: byte = row*128 + ((kk*4+lh)^(row&7))*16, row&7 == lr&7
  const int key = (lr & 7) << 4;
  const int sb0 = ((0 + lh) << 4) ^ key;  // kk=0
  const int sb1 = ((4 + lh) << 4) ^ key;  // kk=1
  const int arow = (wm * 64 + lr) * 128;
  const int brow = 32768 + (wn * 32 + lr) * 128;

  f32x4 acc[8][4];
#pragma unroll
  for (int m = 0; m < 8; ++m)
#pragma unroll
    for (int n = 0; n < 4; ++n) acc[m][n] = (f32x4){0.f, 0.f, 0.f, 0.f};

  const int NT = K >> 6;

  // prologue: tile 0 halves in steady-state issue order A0,B0,B1,A1
  stageA(0, 0, 0); stageB(0, 0, 0); stageB(1, 0, 0); stageA(1, 0, 0);
  asm volatile("s_waitcnt vmcnt(4)" ::: "memory");  // A0,B0 landed; B1,A1 fly
  __builtin_amdgcn_s_barrier();
  __builtin_amdgcn_sched_barrier(0);

  for (int t = 0; t < NT; ++t) {
    const int cur = t & 1, nxt = cur ^ 1;
    const char* Lb = (const char*)lds + cur * 65536;
    const bool pf = (t + 1 < NT);

    short8 a[4][2], b0[2][2], b1[2][2];

    // ---- P0: quadrant (0,0); reads A0,B0; stage A0(t+1) ----
#pragma unroll
    for (int m = 0; m < 4; ++m) {
      a[m][0] = *(const short8*)(Lb + arow + m * 2048 + sb0);
      a[m][1] = *(const short8*)(Lb + arow + m * 2048 + sb1);
    }
#pragma unroll
    for (int n = 0; n < 2; ++n) {
      b0[n][0] = *(const short8*)(Lb + brow + n * 2048 + sb0);
      b0[n][1] = *(const short8*)(Lb + brow + n * 2048 + sb1);
    }
    if (pf) stageA(0, t + 1, nxt);
    asm volatile("s_waitcnt lgkmcnt(0)" ::: "memory");
    __builtin_amdgcn_sched_barrier(0);
    __builtin_amdgcn_s_setprio(1);
#pragma unroll
    for (int m = 0; m < 4; ++m)
#pragma unroll
      for (int n = 0; n < 2; ++n) {
        acc[m][n] = __builtin_amdgcn_mfma_f32_16x16x32_bf16(a[m][0], b0[n][0], acc[m][n], 0, 0, 0);
        acc[m][n] = __builtin_amdgcn_mfma_f32_16x16x32_bf16(a[m][1], b0[n][1], acc[m][n], 0, 0, 0);
      }
    __builtin_amdgcn_s_setprio(0);
    if (pf) { asm volatile("s_waitcnt vmcnt(4)" ::: "memory"); }
    else    { asm volatile("s_waitcnt vmcnt(2)" ::: "memory"); }
    __builtin_amdgcn_s_barrier();
    __builtin_amdgcn_sched_barrier(0);

    // ---- P1: quadrant (0,1); reads B1; stage B0(t+1) ----
#pragma unroll
    for (int n = 0; n < 2; ++n) {
      b1[n][0] = *(const short8*)(Lb + brow + 16384 + n * 2048 + sb0);
      b1[n][1] = *(const short8*)(Lb + brow + 16384 + n * 2048 + sb1);
    }
    if (pf) stageB(0, t + 1, nxt);
    asm volatile("s_waitcnt lgkmcnt(0)" ::: "memory");
    __builtin_amdgcn_sched_barrier(0);
    __builtin_amdgcn_s_setprio(1);
#pragma unroll
    for (int m = 0; m < 4; ++m)
#pragma unroll
      for (int n = 0; n < 2; ++n) {
        acc[m][2 + n] = __builtin_amdgcn_mfma_f32_16x16x32_bf16(a[m][0], b1[n][0], acc[m][2 + n], 0, 0, 0);
        acc[m][2 + n] = __builtin_amdgcn_mfma_f32_16x16x32_bf16(a[m][1], b1[n][1], acc[m][2 + n], 0, 0, 0);
      }
    __builtin_amdgcn_s_setprio(0);
    if (pf) { asm volatile("s_waitcnt vmcnt(4)" ::: "memory"); }
    else    { asm volatile("s_waitcnt vmcnt(0)" ::: "memory"); }
    __builtin_amdgcn_s_barrier();
    __builtin_amdgcn_sched_barrier(0);

    // ---- P2: quadrant (1,0); reads A1; stage B1(t+1) ----
#pragma unroll
    for (int m = 0; m < 4; ++m) {
      a[m][0] = *(const short8*)(Lb + 16384 + arow + m * 2048 + sb0);
      a[m][1] = *(const short8*)(Lb + 16384 + arow + m * 2048 + sb1);
    }
    if (pf) stageB(1, t + 1, nxt);
    asm volatile("s_waitcnt lgkmcnt(0)" ::: "memory");
    __builtin_amdgcn_sched_barrier(0);
    __builtin_amdgcn_s_setprio(1);
#pragma unroll
    for (int m = 0; m < 4; ++m)
#pragma unroll
      for (int n = 0; n < 2; ++n) {
        acc[4 + m][n] = __builtin_amdgcn_mfma_f32_16x16x32_bf16(a[m][0], b0[n][0], acc[4 + m][n], 0, 0, 0);
        acc[4 + m][n] = __builtin_amdgcn_mfma_f32_16x16x32_bf16(a[m][1], b0[n][1], acc[4 + m][n], 0, 0, 0);
      }
    __builtin_amdgcn_s_setprio(0);
    if (pf) { asm volatile("s_waitcnt vmcnt(4)" ::: "memory"); }
    __builtin_amdgcn_s_barrier();
    __builtin_amdgcn_sched_barrier(0);

    // ---- P3: quadrant (1,1); no reads; stage A1(t+1) ----
    if (pf) stageA(1, t + 1, nxt);
    __builtin_amdgcn_s_setprio(1);
#pragma unroll
    for (int m = 0; m < 4; ++m)
#pragma unroll
      for (int n = 0; n < 2; ++n) {
        acc[4 + m][2 + n] = __builtin_amdgcn_mfma_f32_16x16x32_bf16(a[m][0], b1[n][0], acc[4 + m][2 + n], 0, 0, 0);
        acc[4 + m][2 + n] = __builtin_amdgcn_mfma_f32_16x16x32_bf16(a[m][1], b1[n][1], acc[4 + m][2 + n], 0, 0, 0);
      }
    __builtin_amdgcn_s_setprio(0);
    if (pf) { asm volatile("s_waitcnt vmcnt(4)" ::: "memory"); }
    __builtin_amdgcn_s_barrier();
    __builtin_amdgcn_sched_barrier(0);
  }

  // ---- epilogue ----
  // row = bm*256 + mh*128 + wm*64 + ms*16 + lh*4 + i ; col = bn*256 + nh*128 + wn*32 + ns*16 + lr
  const int r0 = bm * 256 + wm * 64 + lh * 4;
  const int c0 = bn * 256 + wn * 32 + lr;

  if constexpr (VSPLIT) {
    if (bn * 256 >= 1024) {
      // V half -> transposed vT[(b*8+head)*128+d][s]
#pragma unroll
      for (int mi = 0; mi < 8; ++mi) {
        const int row_base = r0 + (mi >> 2) * 128 + (mi & 3) * 16;
        const int b = row_base >> 9;
        const int s = row_base & 511;
        float mk[4];
#pragma unroll
        for (int i = 0; i < 4; ++i) mk[i] = rowmask[row_base + i];
#pragma unroll
        for (int ni = 0; ni < 4; ++ni) {
          const int col = c0 + (ni >> 1) * 128 + (ni & 1) * 16;
          const float bv = bias[col];
          const int vcol = col - 1024;
          u16* vp = vTout + ((size_t)(b * 8 + (vcol >> 7)) * 128 + (vcol & 127)) * 512 + s;
          ushort4 o;
          o.x = f2bf((acc[mi][ni][0] + bv) * mk[0]);
          o.y = f2bf((acc[mi][ni][1] + bv) * mk[1]);
          o.z = f2bf((acc[mi][ni][2] + bv) * mk[2]);
          o.w = f2bf((acc[mi][ni][3] + bv) * mk[3]);
          *(ushort4*)vp = o;
        }
      }
      return;
    }
  }

#pragma unroll
  for (int mi = 0; mi < 8; ++mi) {
    const int row_base = r0 + (mi >> 2) * 128 + (mi & 3) * 16;
#pragma unroll
    for (int i = 0; i < 4; ++i) {
      const int row = row_base + i;
      float msk = 1.f;
      if constexpr (MASK) msk = rowmask[row];
#pragma unroll
      for (int ni = 0; ni < 4; ++ni) {
        const int col = c0 + (ni >> 1) * 128 + (ni & 1) * 16;
        float v = (acc[mi][ni][i] + bias[col]) * msk;
        if constexpr (OUTBF)
          ((u16*)Cout)[(size_t)row * ldc + col] = f2bf(v);
        else
          ((float*)Cout)[(size_t)row * ldc + col] = v;
      }
    }
  }
}

// ---------------- flash attention (unchanged from passing round 3) ----------------
__global__ __launch_bounds__(256) void attn_fwd(const u16* __restrict__ q,
                                                const u16* __restrict__ kbuf,
                                                const u16* __restrict__ vT,
                                                const float* __restrict__ smask,
                                                u16* __restrict__ cat) {
  __shared__ __align__(16) u16 lds[20480];
  u16* Ks = lds;            // [64 s][128 d]   16KB
  u16* Vt = lds + 8192;     // [128 d][64 s]   16KB
  u16* Ps = lds + 16384;    // 4 waves x [16 t][64 s] swizzled, 8KB
  const int tid = threadIdx.x;
  const int lane = tid & 63;
  const int w = tid >> 6;
  const int lr = lane & 15, lh = lane >> 4;
  const int bh = blockIdx.x & 255;
  const int qb = blockIdx.x >> 8;
  const int b = bh >> 3;
  const int h = bh & 7;
  const int t0 = qb * 64 + w * 16;
  const float SCALE = 0.08838834764831845f;  // 1/sqrt(128)

  const u16* kbase = kbuf + (size_t)(b * 512) * 1024 + h * 128;
  const u16* vbase = vT + (size_t)bh * 128 * 512;

  short8 qf[4];
  {
    const u16* qp = q + (size_t)(b * 512 + t0 + lr) * 1024 + h * 128 + lh * 8;
#pragma unroll
    for (int kc = 0; kc < 4; ++kc) qf[kc] = *(const short8*)(qp + kc * 32);
  }

  f32x4 o[8];
#pragma unroll
  for (int dt = 0; dt < 8; ++dt) o[dt] = (f32x4){0.f, 0.f, 0.f, 0.f};
  float m_run[4], l_run[4];
#pragma unroll
  for (int i = 0; i < 4; ++i) { m_run[i] = -1e30f; l_run[i] = 0.f; }

  for (int s0 = 0; s0 < 512; s0 += 64) {
    __syncthreads();
#pragma unroll
    for (int it = 0; it < 4; ++it) {
      int idx = it * 256 + tid;
      int kr = idx >> 4, ks = idx & 15;
      gload16(kbase + (size_t)(s0 + kr) * 1024 + ((ks ^ (kr & 7)) * 8), (char*)Ks + idx * 16);
      int vr = idx >> 3, vs = idx & 7;
      gload16(vbase + (size_t)vr * 512 + s0 + ((vs ^ (vr & 7)) * 8), (char*)Vt + idx * 16);
    }
    asm volatile("s_waitcnt vmcnt(0)" ::: "memory");
    __syncthreads();

    f32x4 sc[4];
#pragma unroll
    for (int st = 0; st < 4; ++st) {
      f32x4 c = (f32x4){0.f, 0.f, 0.f, 0.f};
      const int row = st * 16 + lr;
#pragma unroll
      for (int kc = 0; kc < 4; ++kc) {
        short8 kb = *(const short8*)((const char*)Ks + row * 256 +
                                     ((kc * 64 + lh * 16) ^ ((row & 7) << 4)));
        c = __builtin_amdgcn_mfma_f32_16x16x32_bf16(qf[kc], kb, c, 0, 0, 0);
      }
      sc[st] = c;
    }

    float cm[4];
#pragma unroll
    for (int st = 0; st < 4; ++st) cm[st] = smask[b * 512 + s0 + st * 16 + lr];

    float pv[4][4], mx[4];
#pragma unroll
    for (int i = 0; i < 4; ++i) mx[i] = -1e30f;
#pragma unroll
    for (int st = 0; st < 4; ++st)
#pragma unroll
      for (int i = 0; i < 4; ++i) {
        float v = (cm[st] != 0.f) ? sc[st][i] * SCALE : -1e30f;
        pv[st][i] = v;
        mx[i] = fmaxf(mx[i], v);
      }
#pragma unroll
    for (int off = 1; off < 16; off <<= 1)
#pragma unroll
      for (int i = 0; i < 4; ++i) mx[i] = fmaxf(mx[i], __shfl_xor(mx[i], off));

    float m_new[4], scl[4], rs[4];
#pragma unroll
    for (int i = 0; i < 4; ++i) {
      m_new[i] = fmaxf(m_run[i], mx[i]);
      scl[i] = __expf(m_run[i] - m_new[i]);
      rs[i] = 0.f;
    }
#pragma unroll
    for (int st = 0; st < 4; ++st)
#pragma unroll
      for (int i = 0; i < 4; ++i) {
        float p = (cm[st] != 0.f) ? __expf(pv[st][i] - m_new[i]) : 0.f;
        pv[st][i] = p;
        rs[i] += p;
      }
#pragma unroll
    for (int off = 1; off < 16; off <<= 1)
#pragma unroll
      for (int i = 0; i < 4; ++i) rs[i] += __shfl_xor(rs[i], off);
#pragma unroll
    for (int i = 0; i < 4; ++i) {
      l_run[i] = l_run[i] * scl[i] + rs[i];
      m_run[i] = m_new[i];
    }
#pragma unroll
    for (int dt = 0; dt < 8; ++dt)
#pragma unroll
      for (int i = 0; i < 4; ++i) o[dt][i] *= scl[i];

#pragma unroll
    for (int st = 0; st < 4; ++st)
#pragma unroll
      for (int i = 0; i < 4; ++i) {
        const int prow = lh * 4 + i;
        Ps[w * 1024 + prow * 64 + (((st * 2 + (lr >> 3)) ^ (prow & 7)) * 8) + (lr & 7)] =
            f2bf(pv[st][i]);
      }

    short8 pa[2];
#pragma unroll
    for (int s2 = 0; s2 < 2; ++s2)
      pa[s2] = *(const short8*)(Ps + w * 1024 + lr * 64 + (((s2 * 4 + lh) ^ (lr & 7)) * 8));
#pragma unroll
    for (int dt = 0; dt < 8; ++dt) {
#pragma unroll
      for (int s2 = 0; s2 < 2; ++s2) {
        const int row = dt * 16 + lr;
        short8 vb = *(const short8*)((const char*)Vt + row * 128 +
                                     ((s2 * 64 + lh * 16) ^ ((row & 7) << 4)));
        o[dt] = __builtin_amdgcn_mfma_f32_16x16x32_bf16(pa[s2], vb, o[dt], 0, 0, 0);
      }
    }
  }

  float inv[4];
#pragma unroll
  for (int i = 0; i < 4; ++i) inv[i] = 1.f / l_run[i];
  u16* outp = cat + (size_t)(b * 512 + t0 + lh * 4) * 2048 + 1024 + h * 128 + lr;
#pragma unroll
  for (int dt = 0; dt < 8; ++dt)
#pragma unroll
    for (int i = 0; i < 4; ++i)
      outp[(size_t)i * 2048 + dt * 16] = f2bf(o[dt][i] * inv[i]);
}

// ---------------- launcher ----------------
extern "C" void kernel_launch(void* const* d_in, const int* in_sizes, int n_in,
                              void* d_out, int out_size, void* d_ws, size_t ws_size,
                              hipStream_t stream) {
  (void)in_sizes; (void)n_in; (void)out_size; (void)ws_size;
  const float* src      = (const float*)d_in[0];
  const float* tgt      = (const float*)d_in[1];
  const float* src_mask = (const float*)d_in[2];
  const float* tgt_mask = (const float*)d_in[3];
  const float* W_src    = (const float*)d_in[4];
  const float* b_src    = (const float*)d_in[5];
  const float* W_tgt    = (const float*)d_in[6];
  const float* b_tgt    = (const float*)d_in[7];
  const float* W_out    = (const float*)d_in[8];
  const float* b_out    = (const float*)d_in[9];

  char* ws = (char*)d_ws;
  u16* catb = (u16*)(ws);                 // [16384,2048] (src_bf16, then concat[tgt|upd])
  u16* kbuf = (u16*)(ws + 67108864);      // [16384,1024] K
  u16* vTb  = (u16*)(ws + 100663296);     // [256*128,512] V^T
  u16* qbuf = (u16*)(ws + 134217728);     // [16384,1024] Q
  u16* wsrc = (u16*)(ws + 167772160);     // [2048,2048]
  u16* wtgt = (u16*)(ws + 176160768);     // [1024,1024]
  u16* wout = (u16*)(ws + 178257920);     // [1024,2048]

  cvt_f32_bf16<<<2048, 256, 0, stream>>>(src, catb, 16384 * 2048 / 4);
  cvt_f32_bf16<<<1024, 256, 0, stream>>>(W_src, wsrc, 2048 * 2048 / 4);
  cvt_f32_bf16<<<256, 256, 0, stream>>>(W_tgt, wtgt, 1024 * 1024 / 4);
  cvt_f32_bf16<<<512, 256, 0, stream>>>(W_out, wout, 1024 * 2048 / 4);

  // GEMM1: (src @ W_src^T + b_src) * src_mask -> K half to kbuf, V half transposed to vTb
  gemm256<true, true, true><<<512, 512, 0, stream>>>(catb, 2048, wsrc, b_src, src_mask,
                                                     kbuf, 1024, 8, 2048, vTb);

  // tgt -> bf16 into concat buffer first half (src_bf16 now dead)
  cvt_tgt_strided<<<1024, 256, 0, stream>>>(tgt, catb, 16384 * 1024 / 4);

  // GEMM2: q = (tgt @ W_tgt^T + b_tgt) * tgt_mask    [16384,1024]
  gemm256<true, true, false><<<256, 512, 0, stream>>>(catb, 2048, wtgt, b_tgt, tgt_mask,
                                                      qbuf, 1024, 4, 1024, nullptr);

  // attention -> writes upd half of concat buffer
  attn_fwd<<<2048, 256, 0, stream>>>(qbuf, kbuf, vTb, src_mask, catb);

  // GEMM3: out = concat[tgt|upd] @ W_out^T + b_out   [16384,1024] fp32
  gemm256<false, false, false><<<256, 512, 0, stream>>>(catb, 2048, wout, b_out, nullptr,
                                                        (float*)d_out, 1024, 4, 2048, nullptr);
}

// Round 5
// 391.549 us; speedup vs baseline: 1.6678x; 1.0026x over previous
//
#include <hip/hip_runtime.h>

typedef __attribute__((ext_vector_type(4))) float f32x4;
typedef __attribute__((ext_vector_type(8))) short short8;
typedef unsigned short u16;

// ---------------- helpers ----------------
__device__ __forceinline__ u16 f2bf(float f) {
  unsigned int u = __float_as_uint(f);
  return (u16)((u + 0x7fffu + ((u >> 16) & 1u)) >> 16);  // RNE
}

__device__ __forceinline__ void gload16(const void* g, void* l) {
  __builtin_amdgcn_global_load_lds((const __attribute__((address_space(1))) void*)g,
                                   (__attribute__((address_space(3))) void*)l, 16, 0, 0);
}

// ---------------- converts ----------------
__global__ void cvt_f32_bf16(const float* __restrict__ in, u16* __restrict__ out, int n4) {
  int i = blockIdx.x * blockDim.x + threadIdx.x;
  int stride = gridDim.x * blockDim.x;
  for (; i < n4; i += stride) {
    float4 v = ((const float4*)in)[i];
    ushort4 o;
    o.x = f2bf(v.x); o.y = f2bf(v.y); o.z = f2bf(v.z); o.w = f2bf(v.w);
    ((ushort4*)out)[i] = o;
  }
}

// tgt [16384,1024] f32 -> cat[row*2048 + c] bf16 (first half of concat buffer)
__global__ void cvt_tgt_strided(const float* __restrict__ in, u16* __restrict__ cat, int n4) {
  int i = blockIdx.x * blockDim.x + threadIdx.x;
  int stride = gridDim.x * blockDim.x;
  for (; i < n4; i += stride) {
    int e = i * 4;
    int row = e >> 10;
    int c = e & 1023;
    float4 v = ((const float4*)in)[i];
    ushort4 o;
    o.x = f2bf(v.x); o.y = f2bf(v.y); o.z = f2bf(v.z); o.w = f2bf(v.w);
    *(ushort4*)(cat + (size_t)row * 2048 + c) = o;
  }
}

// ---------------- GEMM 256x256, BK=64, 8 waves, read-ahead counted-lgkm pipeline ------
// C[M,N] = A[M,K] * W[N,K]^T (+bias[n]) (*rowmask[m])
// LDS: 2 buffers x 64KB (A[2 halves][128 rows][64k] + B[2 halves][128][64]); 16B slot
// swizzle within each 128B row: slot ^= (row&7).
// Phase p computes quadrant Qp of the K-tile while ISSUING the ds_reads for phase p+1
// (counted lgkmcnt so only the previous phase's reads are drained). Reads thus land
// under the MFMA cluster instead of in front of it. Stage: P0:A0'+B0', P1:B1', P2:A1'
// (>=3-phase landing windows); vmcnt drains: end-P0:4, end-P2:4, end-P3:2.
template <bool MASK, bool OUTBF, bool VSPLIT>
__global__ __launch_bounds__(512) void gemm256(const u16* __restrict__ A, int lda,
                                               const u16* __restrict__ W,
                                               const float* __restrict__ bias,
                                               const float* __restrict__ rowmask,
                                               void* __restrict__ Cout, int ldc,
                                               int nbn, int K,
                                               u16* __restrict__ vTout) {
  __shared__ __align__(16) u16 lds[2 * 32768];  // 128 KiB
  const int tid = threadIdx.x;
  const int lane = tid & 63;
  const int wid = tid >> 6;
  const int lr = lane & 15, lh = lane >> 4;
  const int wm = wid >> 2;  // 0..1
  const int wn = wid & 3;   // 0..3

  // XCD-aware block swizzle (nwg % 8 == 0 for all our shapes)
  const int nwg = gridDim.x;
  const int cpx = nwg >> 3;
  const int bid = (blockIdx.x & 7) * cpx + (blockIdx.x >> 3);
  const int bm = bid / nbn;
  const int bn = bid - bm * nbn;

  // staging thread mapping: chunk i = c*512+tid; row_in_half = i>>3, slot = i&7,
  // source col16 = slot ^ (row&7). (row+64)&7 == row&7 so scol shared by both chunks.
  const int srow = tid >> 3;
  const int scol = ((tid & 7) ^ (srow & 7)) << 3;
  const u16* As0 = A + (size_t)(bm * 256 + srow) * lda + scol;
  const u16* Ws0 = W + (size_t)(bn * 256 + srow) * K + scol;

  auto stageA = [&](int h, int t, int buf) {
    char* d = (char*)lds + buf * 65536 + h * 16384 + tid * 16;
    const u16* s = As0 + (size_t)(h * 128) * lda + t * 64;
    gload16(s, d);
    gload16(s + (size_t)64 * lda, d + 8192);
  };
  auto stageB = [&](int h, int t, int buf) {
    char* d = (char*)lds + buf * 65536 + 32768 + h * 16384 + tid * 16;
    const u16* s = Ws0 + (size_t)(h * 128) * K + t * 64;
    gload16(s, d);
    gload16(s + (size_t)64 * K, d + 8192);
  };

  // fragment read constants: byte = row*128 + ((kk*4+lh)^(row&7))*16, row&7 == lr&7
  const int key = (lr & 7) << 4;
  const int sb0 = ((0 + lh) << 4) ^ key;  // kk=0
  const int sb1 = ((4 + lh) << 4) ^ key;  // kk=1
  const int arow = (wm * 64 + lr) * 128;
  const int brow = 32768 + (wn * 32 + lr) * 128;

  f32x4 acc[8][4];
#pragma unroll
  for (int m = 0; m < 8; ++m)
#pragma unroll
    for (int n = 0; n < 4; ++n) acc[m][n] = (f32x4){0.f, 0.f, 0.f, 0.f};

  const int NT = K >> 6;

  // prologue: stage all 4 halves of tile 0 (order A0,B0,B1,A1)
  stageA(0, 0, 0); stageB(0, 0, 0); stageB(1, 0, 0); stageA(1, 0, 0);
  asm volatile("s_waitcnt vmcnt(2)" ::: "memory");  // A0,B0,B1 landed; A1 in flight
  __builtin_amdgcn_s_barrier();
  __builtin_amdgcn_sched_barrier(0);

  short8 a[4][2], a2[4][2], b0[2][2], b1[2][2];
  // initial R0: A0,B0 fragments of tile 0 (12 ds_reads outstanding at P0 entry)
  {
    const char* Lb = (const char*)lds;
#pragma unroll
    for (int m = 0; m < 4; ++m) {
      a[m][0] = *(const short8*)(Lb + arow + m * 2048 + sb0);
      a[m][1] = *(const short8*)(Lb + arow + m * 2048 + sb1);
    }
#pragma unroll
    for (int n = 0; n < 2; ++n) {
      b0[n][0] = *(const short8*)(Lb + brow + n * 2048 + sb0);
      b0[n][1] = *(const short8*)(Lb + brow + n * 2048 + sb1);
    }
  }

  for (int t = 0; t < NT; ++t) {
    const int cur = t & 1, nxt = cur ^ 1;
    const char* Lb = (const char*)lds + cur * 65536;
    const char* Ln = (const char*)lds + nxt * 65536;
    const bool pf = (t + 1 < NT);

    // ---- P0: MFMA Q00(a,b0); read-ahead b1 (4); stage A0',B0' ----
#pragma unroll
    for (int n = 0; n < 2; ++n) {
      b1[n][0] = *(const short8*)(Lb + brow + 16384 + n * 2048 + sb0);
      b1[n][1] = *(const short8*)(Lb + brow + 16384 + n * 2048 + sb1);
    }
    if (pf) { stageA(0, t + 1, nxt); stageB(0, t + 1, nxt); }
    asm volatile("s_waitcnt lgkmcnt(4)" ::: "memory");  // R0 drained, b1 in flight
    __builtin_amdgcn_sched_barrier(0);
    __builtin_amdgcn_s_setprio(1);
#pragma unroll
    for (int m = 0; m < 4; ++m)
#pragma unroll
      for (int n = 0; n < 2; ++n) {
        acc[m][n] = __builtin_amdgcn_mfma_f32_16x16x32_bf16(a[m][0], b0[n][0], acc[m][n], 0, 0, 0);
        acc[m][n] = __builtin_amdgcn_mfma_f32_16x16x32_bf16(a[m][1], b0[n][1], acc[m][n], 0, 0, 0);
      }
    __builtin_amdgcn_s_setprio(0);
    if (pf) { asm volatile("s_waitcnt vmcnt(4)" ::: "memory"); }   // drain A1'(t) of prev tile
    else    { asm volatile("s_waitcnt vmcnt(0)" ::: "memory"); }
    __builtin_amdgcn_s_barrier();
    __builtin_amdgcn_sched_barrier(0);

    // ---- P1: MFMA Q01(a,b1); read-ahead a2 (8); stage B1' ----
#pragma unroll
    for (int m = 0; m < 4; ++m) {
      a2[m][0] = *(const short8*)(Lb + 16384 + arow + m * 2048 + sb0);
      a2[m][1] = *(const short8*)(Lb + 16384 + arow + m * 2048 + sb1);
    }
    if (pf) stageB(1, t + 1, nxt);
    asm volatile("s_waitcnt lgkmcnt(8)" ::: "memory");  // b1 drained, a2 in flight
    __builtin_amdgcn_sched_barrier(0);
    __builtin_amdgcn_s_setprio(1);
#pragma unroll
    for (int m = 0; m < 4; ++m)
#pragma unroll
      for (int n = 0; n < 2; ++n) {
        acc[m][2 + n] = __builtin_amdgcn_mfma_f32_16x16x32_bf16(a[m][0], b1[n][0], acc[m][2 + n], 0, 0, 0);
        acc[m][2 + n] = __builtin_amdgcn_mfma_f32_16x16x32_bf16(a[m][1], b1[n][1], acc[m][2 + n], 0, 0, 0);
      }
    __builtin_amdgcn_s_setprio(0);
    __builtin_amdgcn_s_barrier();
    __builtin_amdgcn_sched_barrier(0);

    // ---- P2: MFMA Q10(a2,b0); stage A1' ----
    if (pf) stageA(1, t + 1, nxt);
    asm volatile("s_waitcnt lgkmcnt(0)" ::: "memory");  // a2 drained
    __builtin_amdgcn_sched_barrier(0);
    __builtin_amdgcn_s_setprio(1);
#pragma unroll
    for (int m = 0; m < 4; ++m)
#pragma unroll
      for (int n = 0; n < 2; ++n) {
        acc[4 + m][n] = __builtin_amdgcn_mfma_f32_16x16x32_bf16(a2[m][0], b0[n][0], acc[4 + m][n], 0, 0, 0);
        acc[4 + m][n] = __builtin_amdgcn_mfma_f32_16x16x32_bf16(a2[m][1], b0[n][1], acc[4 + m][n], 0, 0, 0);
      }
    __builtin_amdgcn_s_setprio(0);
    if (pf) { asm volatile("s_waitcnt vmcnt(4)" ::: "memory"); }   // drain A0',B0' for P3 reads
    else    { asm volatile("s_waitcnt vmcnt(0)" ::: "memory"); }
    __builtin_amdgcn_s_barrier();
    __builtin_amdgcn_sched_barrier(0);

    // ---- P3: MFMA Q11(a2,b1); read-ahead next tile's a,b0 from other buffer ----
    if (pf) {
#pragma unroll
      for (int m = 0; m < 4; ++m) {
        a[m][0] = *(const short8*)(Ln + arow + m * 2048 + sb0);
        a[m][1] = *(const short8*)(Ln + arow + m * 2048 + sb1);
      }
#pragma unroll
      for (int n = 0; n < 2; ++n) {
        b0[n][0] = *(const short8*)(Ln + brow + n * 2048 + sb0);
        b0[n][1] = *(const short8*)(Ln + brow + n * 2048 + sb1);
      }
    }
    __builtin_amdgcn_sched_barrier(0);
    __builtin_amdgcn_s_setprio(1);
#pragma unroll
    for (int m = 0; m < 4; ++m)
#pragma unroll
      for (int n = 0; n < 2; ++n) {
        acc[4 + m][2 + n] = __builtin_amdgcn_mfma_f32_16x16x32_bf16(a2[m][0], b1[n][0], acc[4 + m][2 + n], 0, 0, 0);
        acc[4 + m][2 + n] = __builtin_amdgcn_mfma_f32_16x16x32_bf16(a2[m][1], b1[n][1], acc[4 + m][2 + n], 0, 0, 0);
      }
    __builtin_amdgcn_s_setprio(0);
    if (pf) { asm volatile("s_waitcnt vmcnt(2)" ::: "memory"); }   // drain B1' for next P0 reads
    __builtin_amdgcn_s_barrier();
    __builtin_amdgcn_sched_barrier(0);
  }

  // ---- epilogue ----
  // row = bm*256 + mh*128 + wm*64 + ms*16 + lh*4 + i ; col = bn*256 + nh*128 + wn*32 + ns*16 + lr
  const int r0 = bm * 256 + wm * 64 + lh * 4;
  const int c0 = bn * 256 + wn * 32 + lr;

  if constexpr (VSPLIT) {
    if (bn * 256 >= 1024) {
      // V half -> transposed vT[(b*8+head)*128+d][s]
#pragma unroll
      for (int mi = 0; mi < 8; ++mi) {
        const int row_base = r0 + (mi >> 2) * 128 + (mi & 3) * 16;
        const int b = row_base >> 9;
        const int s = row_base & 511;
        float mk[4];
#pragma unroll
        for (int i = 0; i < 4; ++i) mk[i] = rowmask[row_base + i];
#pragma unroll
        for (int ni = 0; ni < 4; ++ni) {
          const int col = c0 + (ni >> 1) * 128 + (ni & 1) * 16;
          const float bv = bias[col];
          const int vcol = col - 1024;
          u16* vp = vTout + ((size_t)(b * 8 + (vcol >> 7)) * 128 + (vcol & 127)) * 512 + s;
          ushort4 o;
          o.x = f2bf((acc[mi][ni][0] + bv) * mk[0]);
          o.y = f2bf((acc[mi][ni][1] + bv) * mk[1]);
          o.z = f2bf((acc[mi][ni][2] + bv) * mk[2]);
          o.w = f2bf((acc[mi][ni][3] + bv) * mk[3]);
          *(ushort4*)vp = o;
        }
      }
      return;
    }
  }

#pragma unroll
  for (int mi = 0; mi < 8; ++mi) {
    const int row_base = r0 + (mi >> 2) * 128 + (mi & 3) * 16;
#pragma unroll
    for (int i = 0; i < 4; ++i) {
      const int row = row_base + i;
      float msk = 1.f;
      if constexpr (MASK) msk = rowmask[row];
#pragma unroll
      for (int ni = 0; ni < 4; ++ni) {
        const int col = c0 + (ni >> 1) * 128 + (ni & 1) * 16;
        float v = (acc[mi][ni][i] + bias[col]) * msk;
        if constexpr (OUTBF)
          ((u16*)Cout)[(size_t)row * ldc + col] = f2bf(v);
        else
          ((float*)Cout)[(size_t)row * ldc + col] = v;
      }
    }
  }
}

// ---------------- flash attention (unchanged from passing round 3) ----------------
__global__ __launch_bounds__(256) void attn_fwd(const u16* __restrict__ q,
                                                const u16* __restrict__ kbuf,
                                                const u16* __restrict__ vT,
                                                const float* __restrict__ smask,
                                                u16* __restrict__ cat) {
  __shared__ __align__(16) u16 lds[20480];
  u16* Ks = lds;            // [64 s][128 d]   16KB
  u16* Vt = lds + 8192;     // [128 d][64 s]   16KB
  u16* Ps = lds + 16384;    // 4 waves x [16 t][64 s] swizzled, 8KB
  const int tid = threadIdx.x;
  const int lane = tid & 63;
  const int w = tid >> 6;
  const int lr = lane & 15, lh = lane >> 4;
  const int bh = blockIdx.x & 255;
  const int qb = blockIdx.x >> 8;
  const int b = bh >> 3;
  const int h = bh & 7;
  const int t0 = qb * 64 + w * 16;
  const float SCALE = 0.08838834764831845f;  // 1/sqrt(128)

  const u16* kbase = kbuf + (size_t)(b * 512) * 1024 + h * 128;
  const u16* vbase = vT + (size_t)bh * 128 * 512;

  short8 qf[4];
  {
    const u16* qp = q + (size_t)(b * 512 + t0 + lr) * 1024 + h * 128 + lh * 8;
#pragma unroll
    for (int kc = 0; kc < 4; ++kc) qf[kc] = *(const short8*)(qp + kc * 32);
  }

  f32x4 o[8];
#pragma unroll
  for (int dt = 0; dt < 8; ++dt) o[dt] = (f32x4){0.f, 0.f, 0.f, 0.f};
  float m_run[4], l_run[4];
#pragma unroll
  for (int i = 0; i < 4; ++i) { m_run[i] = -1e30f; l_run[i] = 0.f; }

  for (int s0 = 0; s0 < 512; s0 += 64) {
    __syncthreads();
#pragma unroll
    for (int it = 0; it < 4; ++it) {
      int idx = it * 256 + tid;
      int kr = idx >> 4, ks = idx & 15;
      gload16(kbase + (size_t)(s0 + kr) * 1024 + ((ks ^ (kr & 7)) * 8), (char*)Ks + idx * 16);
      int vr = idx >> 3, vs = idx & 7;
      gload16(vbase + (size_t)vr * 512 + s0 + ((vs ^ (vr & 7)) * 8), (char*)Vt + idx * 16);
    }
    asm volatile("s_waitcnt vmcnt(0)" ::: "memory");
    __syncthreads();

    f32x4 sc[4];
#pragma unroll
    for (int st = 0; st < 4; ++st) {
      f32x4 c = (f32x4){0.f, 0.f, 0.f, 0.f};
      const int row = st * 16 + lr;
#pragma unroll
      for (int kc = 0; kc < 4; ++kc) {
        short8 kb = *(const short8*)((const char*)Ks + row * 256 +
                                     ((kc * 64 + lh * 16) ^ ((row & 7) << 4)));
        c = __builtin_amdgcn_mfma_f32_16x16x32_bf16(qf[kc], kb, c, 0, 0, 0);
      }
      sc[st] = c;
    }

    float cm[4];
#pragma unroll
    for (int st = 0; st < 4; ++st) cm[st] = smask[b * 512 + s0 + st * 16 + lr];

    float pv[4][4], mx[4];
#pragma unroll
    for (int i = 0; i < 4; ++i) mx[i] = -1e30f;
#pragma unroll
    for (int st = 0; st < 4; ++st)
#pragma unroll
      for (int i = 0; i < 4; ++i) {
        float v = (cm[st] != 0.f) ? sc[st][i] * SCALE : -1e30f;
        pv[st][i] = v;
        mx[i] = fmaxf(mx[i], v);
      }
#pragma unroll
    for (int off = 1; off < 16; off <<= 1)
#pragma unroll
      for (int i = 0; i < 4; ++i) mx[i] = fmaxf(mx[i], __shfl_xor(mx[i], off));

    float m_new[4], scl[4], rs[4];
#pragma unroll
    for (int i = 0; i < 4; ++i) {
      m_new[i] = fmaxf(m_run[i], mx[i]);
      scl[i] = __expf(m_run[i] - m_new[i]);
      rs[i] = 0.f;
    }
#pragma unroll
    for (int st = 0; st < 4; ++st)
#pragma unroll
      for (int i = 0; i < 4; ++i) {
        float p = (cm[st] != 0.f) ? __expf(pv[st][i] - m_new[i]) : 0.f;
        pv[st][i] = p;
        rs[i] += p;
      }
#pragma unroll
    for (int off = 1; off < 16; off <<= 1)
#pragma unroll
      for (int i = 0; i < 4; ++i) rs[i] += __shfl_xor(rs[i], off);
#pragma unroll
    for (int i = 0; i < 4; ++i) {
      l_run[i] = l_run[i] * scl[i] + rs[i];
      m_run[i] = m_new[i];
    }
#pragma unroll
    for (int dt = 0; dt < 8; ++dt)
#pragma unroll
      for (int i = 0; i < 4; ++i) o[dt][i] *= scl[i];

#pragma unroll
    for (int st = 0; st < 4; ++st)
#pragma unroll
      for (int i = 0; i < 4; ++i) {
        const int prow = lh * 4 + i;
        Ps[w * 1024 + prow * 64 + (((st * 2 + (lr >> 3)) ^ (prow & 7)) * 8) + (lr & 7)] =
            f2bf(pv[st][i]);
      }

    short8 pa[2];
#pragma unroll
    for (int s2 = 0; s2 < 2; ++s2)
      pa[s2] = *(const short8*)(Ps + w * 1024 + lr * 64 + (((s2 * 4 + lh) ^ (lr & 7)) * 8));
#pragma unroll
    for (int dt = 0; dt < 8; ++dt) {
#pragma unroll
      for (int s2 = 0; s2 < 2; ++s2) {
        const int row = dt * 16 + lr;
        short8 vb = *(const short8*)((const char*)Vt + row * 128 +
                                     ((s2 * 64 + lh * 16) ^ ((row & 7) << 4)));
        o[dt] = __builtin_amdgcn_mfma_f32_16x16x32_bf16(pa[s2], vb, o[dt], 0, 0, 0);
      }
    }
  }

  float inv[4];
#pragma unroll
  for (int i = 0; i < 4; ++i) inv[i] = 1.f / l_run[i];
  u16* outp = cat + (size_t)(b * 512 + t0 + lh * 4) * 2048 + 1024 + h * 128 + lr;
#pragma unroll
  for (int dt = 0; dt < 8; ++dt)
#pragma unroll
    for (int i = 0; i < 4; ++i)
      outp[(size_t)i * 2048 + dt * 16] = f2bf(o[dt][i] * inv[i]);
}

// ---------------- launcher ----------------
extern "C" void kernel_launch(void* const* d_in, const int* in_sizes, int n_in,
                              void* d_out, int out_size, void* d_ws, size_t ws_size,
                              hipStream_t stream) {
  (void)in_sizes; (void)n_in; (void)out_size; (void)ws_size;
  const float* src      = (const float*)d_in[0];
  const float* tgt      = (const float*)d_in[1];
  const float* src_mask = (const float*)d_in[2];
  const float* tgt_mask = (const float*)d_in[3];
  const float* W_src    = (const float*)d_in[4];
  const float* b_src    = (const float*)d_in[5];
  const float* W_tgt    = (const float*)d_in[6];
  const float* b_tgt    = (const float*)d_in[7];
  const float* W_out    = (const float*)d_in[8];
  const float* b_out    = (const float*)d_in[9];

  char* ws = (char*)d_ws;
  u16* catb = (u16*)(ws);                 // [16384,2048] (src_bf16, then concat[tgt|upd])
  u16* kbuf = (u16*)(ws + 67108864);      // [16384,1024] K
  u16* vTb  = (u16*)(ws + 100663296);     // [256*128,512] V^T
  u16* qbuf = (u16*)(ws + 134217728);     // [16384,1024] Q
  u16* wsrc = (u16*)(ws + 167772160);     // [2048,2048]
  u16* wtgt = (u16*)(ws + 176160768);     // [1024,1024]
  u16* wout = (u16*)(ws + 178257920);     // [1024,2048]

  cvt_f32_bf16<<<2048, 256, 0, stream>>>(src, catb, 16384 * 2048 / 4);
  cvt_f32_bf16<<<1024, 256, 0, stream>>>(W_src, wsrc, 2048 * 2048 / 4);
  cvt_f32_bf16<<<256, 256, 0, stream>>>(W_tgt, wtgt, 1024 * 1024 / 4);
  cvt_f32_bf16<<<512, 256, 0, stream>>>(W_out, wout, 1024 * 2048 / 4);

  // GEMM1: (src @ W_src^T + b_src) * src_mask -> K half to kbuf, V half transposed to vTb
  gemm256<true, true, true><<<512, 512, 0, stream>>>(catb, 2048, wsrc, b_src, src_mask,
                                                     kbuf, 1024, 8, 2048, vTb);

  // tgt -> bf16 into concat buffer first half (src_bf16 now dead)
  cvt_tgt_strided<<<1024, 256, 0, stream>>>(tgt, catb, 16384 * 1024 / 4);

  // GEMM2: q = (tgt @ W_tgt^T + b_tgt) * tgt_mask    [16384,1024]
  gemm256<true, true, false><<<256, 512, 0, stream>>>(catb, 2048, wtgt, b_tgt, tgt_mask,
                                                      qbuf, 1024, 4, 1024, nullptr);

  // attention -> writes upd half of concat buffer
  attn_fwd<<<2048, 256, 0, stream>>>(qbuf, kbuf, vTb, src_mask, catb);

  // GEMM3: out = concat[tgt|upd] @ W_out^T + b_out   [16384,1024] fp32
  gemm256<false, false, false><<<256, 512, 0, stream>>>(catb, 2048, wout, b_out, nullptr,
                                                        (float*)d_out, 1024, 4, 2048, nullptr);
}

// Round 6
// 384.195 us; speedup vs baseline: 1.6997x; 1.0191x over previous
//
#include <hip/hip_runtime.h>

typedef __attribute__((ext_vector_type(4))) float f32x4;
typedef __attribute__((ext_vector_type(8))) short short8;
typedef unsigned short u16;

#define SB0() __builtin_amdgcn_sched_barrier(0)

// ---------------- helpers ----------------
__device__ __forceinline__ u16 f2bf(float f) {
  unsigned int u = __float_as_uint(f);
  return (u16)((u + 0x7fffu + ((u >> 16) & 1u)) >> 16);  // RNE
}

__device__ __forceinline__ void gload16(const void* g, void* l) {
  __builtin_amdgcn_global_load_lds((const __attribute__((address_space(1))) void*)g,
                                   (__attribute__((address_space(3))) void*)l, 16, 0, 0);
}

// ---------------- converts ----------------
__global__ void cvt_f32_bf16(const float* __restrict__ in, u16* __restrict__ out, int n4) {
  int i = blockIdx.x * blockDim.x + threadIdx.x;
  int stride = gridDim.x * blockDim.x;
  for (; i < n4; i += stride) {
    float4 v = ((const float4*)in)[i];
    ushort4 o;
    o.x = f2bf(v.x); o.y = f2bf(v.y); o.z = f2bf(v.z); o.w = f2bf(v.w);
    ((ushort4*)out)[i] = o;
  }
}

// tgt [16384,1024] f32 -> cat[row*2048 + c] bf16 (first half of concat buffer)
__global__ void cvt_tgt_strided(const float* __restrict__ in, u16* __restrict__ cat, int n4) {
  int i = blockIdx.x * blockDim.x + threadIdx.x;
  int stride = gridDim.x * blockDim.x;
  for (; i < n4; i += stride) {
    int e = i * 4;
    int row = e >> 10;
    int c = e & 1023;
    float4 v = ((const float4*)in)[i];
    ushort4 o;
    o.x = f2bf(v.x); o.y = f2bf(v.y); o.z = f2bf(v.z); o.w = f2bf(v.w);
    *(ushort4*)(cat + (size_t)row * 2048 + c) = o;
  }
}

// ---------------- GEMM 256x256, BK=64, 8 waves, 1-barrier-per-tile pipeline ----------
// C[M,N] = A[M,K] * W[N,K]^T (+bias[n]) (*rowmask[m])
// LDS: 2 buffers x 64KB (A[2 halves][128 rows][64k] + B[2 halves][128][64]); 16B slot
// swizzle within each 128B row: slot ^= (row&7).
// Per K-tile: ONE s_barrier + ONE vmcnt(0). All fragment reads use per-wave counted
// lgkmcnt (group-pinned with sched_barrier(0)) so waves desynchronize within the tile
// and LDS reads overlap other waves' MFMA clusters. Staging for t+1 is issued at the
// top of tile t (full-tile landing window >> HBM latency -> end vmcnt(0) is cheap).
// Race ledger: each wave's reads of tile t drain at its lgkmcnt(0) BEFORE the barrier;
// t+1 staging writes drain at vmcnt(0) before the barrier; t+2 staging (same buffer as
// t) is issued only after the barrier. One buffer swap per tile (mod 2).
template <bool MASK, bool OUTBF, bool VSPLIT>
__global__ __launch_bounds__(512) void gemm256(const u16* __restrict__ A, int lda,
                                               const u16* __restrict__ W,
                                               const float* __restrict__ bias,
                                               const float* __restrict__ rowmask,
                                               void* __restrict__ Cout, int ldc,
                                               int nbn, int K,
                                               u16* __restrict__ vTout) {
  __shared__ __align__(16) u16 lds[2 * 32768];  // 128 KiB
  const int tid = threadIdx.x;
  const int lane = tid & 63;
  const int wid = tid >> 6;
  const int lr = lane & 15, lh = lane >> 4;
  const int wm = wid >> 2;  // 0..1
  const int wn = wid & 3;   // 0..3

  // XCD-aware block swizzle (nwg % 8 == 0 for all our shapes)
  const int nwg = gridDim.x;
  const int cpx = nwg >> 3;
  const int bid = (blockIdx.x & 7) * cpx + (blockIdx.x >> 3);
  const int bm = bid / nbn;
  const int bn = bid - bm * nbn;

  // staging thread mapping: chunk i = c*512+tid; row_in_half = i>>3, slot = i&7,
  // source col16 = slot ^ (row&7). (row+64)&7 == row&7 so scol shared by both chunks.
  const int srow = tid >> 3;
  const int scol = ((tid & 7) ^ (srow & 7)) << 3;
  const u16* As0 = A + (size_t)(bm * 256 + srow) * lda + scol;
  const u16* Ws0 = W + (size_t)(bn * 256 + srow) * K + scol;

  auto stageA = [&](int h, int t, int buf) {
    char* d = (char*)lds + buf * 65536 + h * 16384 + tid * 16;
    const u16* s = As0 + (size_t)(h * 128) * lda + t * 64;
    gload16(s, d);
    gload16(s + (size_t)64 * lda, d + 8192);
  };
  auto stageB = [&](int h, int t, int buf) {
    char* d = (char*)lds + buf * 65536 + 32768 + h * 16384 + tid * 16;
    const u16* s = Ws0 + (size_t)(h * 128) * K + t * 64;
    gload16(s, d);
    gload16(s + (size_t)64 * K, d + 8192);
  };

  // fragment read constants: byte = row*128 + ((kk*4+lh)^(row&7))*16, row&7 == lr&7
  const int key = (lr & 7) << 4;
  const int sb0 = ((0 + lh) << 4) ^ key;  // kk=0
  const int sb1 = ((4 + lh) << 4) ^ key;  // kk=1
  const int arow = (wm * 64 + lr) * 128;
  const int brow = 32768 + (wn * 32 + lr) * 128;

  f32x4 acc[8][4];
#pragma unroll
  for (int m = 0; m < 8; ++m)
#pragma unroll
    for (int n = 0; n < 4; ++n) acc[m][n] = (f32x4){0.f, 0.f, 0.f, 0.f};

  const int NT = K >> 6;

  // prologue: stage tile 0, drain, barrier
  stageA(0, 0, 0); stageB(0, 0, 0); stageB(1, 0, 0); stageA(1, 0, 0);
  asm volatile("s_waitcnt vmcnt(0)" ::: "memory");
  __builtin_amdgcn_s_barrier();
  SB0();

  for (int t = 0; t < NT; ++t) {
    const int cur = t & 1, nxt = cur ^ 1;
    const char* Lb = (const char*)lds + cur * 65536;
    const bool pf = (t + 1 < NT);

    short8 a[4][2], a2[4][2], b0[2][2], b1[2][2];

    // ---- issue reads a (8), b0 (4); pin group ----
#pragma unroll
    for (int m = 0; m < 4; ++m) {
      a[m][0] = *(const short8*)(Lb + arow + m * 2048 + sb0);
      a[m][1] = *(const short8*)(Lb + arow + m * 2048 + sb1);
    }
#pragma unroll
    for (int n = 0; n < 2; ++n) {
      b0[n][0] = *(const short8*)(Lb + brow + n * 2048 + sb0);
      b0[n][1] = *(const short8*)(Lb + brow + n * 2048 + sb1);
    }
    SB0();
    // ---- issue all staging for t+1 (8 gloads; full-tile landing window) ----
    if (pf) { stageA(0, t + 1, nxt); stageB(0, t + 1, nxt);
              stageB(1, t + 1, nxt); stageA(1, t + 1, nxt); }
    // ---- issue reads b1 (4) ----
#pragma unroll
    for (int n = 0; n < 2; ++n) {
      b1[n][0] = *(const short8*)(Lb + brow + 16384 + n * 2048 + sb0);
      b1[n][1] = *(const short8*)(Lb + brow + 16384 + n * 2048 + sb1);
    }
    SB0();
    asm volatile("s_waitcnt lgkmcnt(4)" ::: "memory");  // a,b0 done; b1 may fly
    SB0();
    __builtin_amdgcn_s_setprio(1);
#pragma unroll
    for (int m = 0; m < 4; ++m)
#pragma unroll
      for (int n = 0; n < 2; ++n) {
        acc[m][n] = __builtin_amdgcn_mfma_f32_16x16x32_bf16(a[m][0], b0[n][0], acc[m][n], 0, 0, 0);
        acc[m][n] = __builtin_amdgcn_mfma_f32_16x16x32_bf16(a[m][1], b0[n][1], acc[m][n], 0, 0, 0);
      }
    __builtin_amdgcn_s_setprio(0);
    // ---- issue reads a2 (8) (interleaves with Q00 in this region) ----
#pragma unroll
    for (int m = 0; m < 4; ++m) {
      a2[m][0] = *(const short8*)(Lb + 16384 + arow + m * 2048 + sb0);
      a2[m][1] = *(const short8*)(Lb + 16384 + arow + m * 2048 + sb1);
    }
    asm volatile("s_waitcnt lgkmcnt(8)" ::: "memory");  // b1 done (FIFO); a2 may fly
    SB0();
    __builtin_amdgcn_s_setprio(1);
#pragma unroll
    for (int m = 0; m < 4; ++m)
#pragma unroll
      for (int n = 0; n < 2; ++n) {
        acc[m][2 + n] = __builtin_amdgcn_mfma_f32_16x16x32_bf16(a[m][0], b1[n][0], acc[m][2 + n], 0, 0, 0);
        acc[m][2 + n] = __builtin_amdgcn_mfma_f32_16x16x32_bf16(a[m][1], b1[n][1], acc[m][2 + n], 0, 0, 0);
      }
    __builtin_amdgcn_s_setprio(0);
    asm volatile("s_waitcnt lgkmcnt(0)" ::: "memory");  // a2 done
    SB0();
    __builtin_amdgcn_s_setprio(1);
#pragma unroll
    for (int m = 0; m < 4; ++m)
#pragma unroll
      for (int n = 0; n < 2; ++n) {
        acc[4 + m][n] = __builtin_amdgcn_mfma_f32_16x16x32_bf16(a2[m][0], b0[n][0], acc[4 + m][n], 0, 0, 0);
        acc[4 + m][n] = __builtin_amdgcn_mfma_f32_16x16x32_bf16(a2[m][1], b0[n][1], acc[4 + m][n], 0, 0, 0);
      }
#pragma unroll
    for (int m = 0; m < 4; ++m)
#pragma unroll
      for (int n = 0; n < 2; ++n) {
        acc[4 + m][2 + n] = __builtin_amdgcn_mfma_f32_16x16x32_bf16(a2[m][0], b1[n][0], acc[4 + m][2 + n], 0, 0, 0);
        acc[4 + m][2 + n] = __builtin_amdgcn_mfma_f32_16x16x32_bf16(a2[m][1], b1[n][1], acc[4 + m][2 + n], 0, 0, 0);
      }
    __builtin_amdgcn_s_setprio(0);
    SB0();
    asm volatile("s_waitcnt vmcnt(0)" ::: "memory");  // t+1 fully staged (issued ~1 tile ago)
    __builtin_amdgcn_s_barrier();
    SB0();
  }

  // ---- epilogue ----
  // row = bm*256 + mh*128 + wm*64 + ms*16 + lh*4 + i ; col = bn*256 + nh*128 + wn*32 + ns*16 + lr
  const int r0 = bm * 256 + wm * 64 + lh * 4;
  const int c0 = bn * 256 + wn * 32 + lr;

  if constexpr (VSPLIT) {
    if (bn * 256 >= 1024) {
      // V half -> transposed vT[(b*8+head)*128+d][s]
#pragma unroll
      for (int mi = 0; mi < 8; ++mi) {
        const int row_base = r0 + (mi >> 2) * 128 + (mi & 3) * 16;
        const int b = row_base >> 9;
        const int s = row_base & 511;
        float mk[4];
#pragma unroll
        for (int i = 0; i < 4; ++i) mk[i] = rowmask[row_base + i];
#pragma unroll
        for (int ni = 0; ni < 4; ++ni) {
          const int col = c0 + (ni >> 1) * 128 + (ni & 1) * 16;
          const float bv = bias[col];
          const int vcol = col - 1024;
          u16* vp = vTout + ((size_t)(b * 8 + (vcol >> 7)) * 128 + (vcol & 127)) * 512 + s;
          ushort4 o;
          o.x = f2bf((acc[mi][ni][0] + bv) * mk[0]);
          o.y = f2bf((acc[mi][ni][1] + bv) * mk[1]);
          o.z = f2bf((acc[mi][ni][2] + bv) * mk[2]);
          o.w = f2bf((acc[mi][ni][3] + bv) * mk[3]);
          *(ushort4*)vp = o;
        }
      }
      return;
    }
  }

#pragma unroll
  for (int mi = 0; mi < 8; ++mi) {
    const int row_base = r0 + (mi >> 2) * 128 + (mi & 3) * 16;
#pragma unroll
    for (int i = 0; i < 4; ++i) {
      const int row = row_base + i;
      float msk = 1.f;
      if constexpr (MASK) msk = rowmask[row];
#pragma unroll
      for (int ni = 0; ni < 4; ++ni) {
        const int col = c0 + (ni >> 1) * 128 + (ni & 1) * 16;
        float v = (acc[mi][ni][i] + bias[col]) * msk;
        if constexpr (OUTBF)
          ((u16*)Cout)[(size_t)row * ldc + col] = f2bf(v);
        else
          ((float*)Cout)[(size_t)row * ldc + col] = v;
      }
    }
  }
}

// ---------------- flash attention (unchanged from passing round 3) ----------------
__global__ __launch_bounds__(256) void attn_fwd(const u16* __restrict__ q,
                                                const u16* __restrict__ kbuf,
                                                const u16* __restrict__ vT,
                                                const float* __restrict__ smask,
                                                u16* __restrict__ cat) {
  __shared__ __align__(16) u16 lds[20480];
  u16* Ks = lds;            // [64 s][128 d]   16KB
  u16* Vt = lds + 8192;     // [128 d][64 s]   16KB
  u16* Ps = lds + 16384;    // 4 waves x [16 t][64 s] swizzled, 8KB
  const int tid = threadIdx.x;
  const int lane = tid & 63;
  const int w = tid >> 6;
  const int lr = lane & 15, lh = lane >> 4;
  const int bh = blockIdx.x & 255;
  const int qb = blockIdx.x >> 8;
  const int b = bh >> 3;
  const int h = bh & 7;
  const int t0 = qb * 64 + w * 16;
  const float SCALE = 0.08838834764831845f;  // 1/sqrt(128)

  const u16* kbase = kbuf + (size_t)(b * 512) * 1024 + h * 128;
  const u16* vbase = vT + (size_t)bh * 128 * 512;

  short8 qf[4];
  {
    const u16* qp = q + (size_t)(b * 512 + t0 + lr) * 1024 + h * 128 + lh * 8;
#pragma unroll
    for (int kc = 0; kc < 4; ++kc) qf[kc] = *(const short8*)(qp + kc * 32);
  }

  f32x4 o[8];
#pragma unroll
  for (int dt = 0; dt < 8; ++dt) o[dt] = (f32x4){0.f, 0.f, 0.f, 0.f};
  float m_run[4], l_run[4];
#pragma unroll
  for (int i = 0; i < 4; ++i) { m_run[i] = -1e30f; l_run[i] = 0.f; }

  for (int s0 = 0; s0 < 512; s0 += 64) {
    __syncthreads();
#pragma unroll
    for (int it = 0; it < 4; ++it) {
      int idx = it * 256 + tid;
      int kr = idx >> 4, ks = idx & 15;
      gload16(kbase + (size_t)(s0 + kr) * 1024 + ((ks ^ (kr & 7)) * 8), (char*)Ks + idx * 16);
      int vr = idx >> 3, vs = idx & 7;
      gload16(vbase + (size_t)vr * 512 + s0 + ((vs ^ (vr & 7)) * 8), (char*)Vt + idx * 16);
    }
    asm volatile("s_waitcnt vmcnt(0)" ::: "memory");
    __syncthreads();

    f32x4 sc[4];
#pragma unroll
    for (int st = 0; st < 4; ++st) {
      f32x4 c = (f32x4){0.f, 0.f, 0.f, 0.f};
      const int row = st * 16 + lr;
#pragma unroll
      for (int kc = 0; kc < 4; ++kc) {
        short8 kb = *(const short8*)((const char*)Ks + row * 256 +
                                     ((kc * 64 + lh * 16) ^ ((row & 7) << 4)));
        c = __builtin_amdgcn_mfma_f32_16x16x32_bf16(qf[kc], kb, c, 0, 0, 0);
      }
      sc[st] = c;
    }

    float cm[4];
#pragma unroll
    for (int st = 0; st < 4; ++st) cm[st] = smask[b * 512 + s0 + st * 16 + lr];

    float pv[4][4], mx[4];
#pragma unroll
    for (int i = 0; i < 4; ++i) mx[i] = -1e30f;
#pragma unroll
    for (int st = 0; st < 4; ++st)
#pragma unroll
      for (int i = 0; i < 4; ++i) {
        float v = (cm[st] != 0.f) ? sc[st][i] * SCALE : -1e30f;
        pv[st][i] = v;
        mx[i] = fmaxf(mx[i], v);
      }
#pragma unroll
    for (int off = 1; off < 16; off <<= 1)
#pragma unroll
      for (int i = 0; i < 4; ++i) mx[i] = fmaxf(mx[i], __shfl_xor(mx[i], off));

    float m_new[4], scl[4], rs[4];
#pragma unroll
    for (int i = 0; i < 4; ++i) {
      m_new[i] = fmaxf(m_run[i], mx[i]);
      scl[i] = __expf(m_run[i] - m_new[i]);
      rs[i] = 0.f;
    }
#pragma unroll
    for (int st = 0; st < 4; ++st)
#pragma unroll
      for (int i = 0; i < 4; ++i) {
        float p = (cm[st] != 0.f) ? __expf(pv[st][i] - m_new[i]) : 0.f;
        pv[st][i] = p;
        rs[i] += p;
      }
#pragma unroll
    for (int off = 1; off < 16; off <<= 1)
#pragma unroll
      for (int i = 0; i < 4; ++i) rs[i] += __shfl_xor(rs[i], off);
#pragma unroll
    for (int i = 0; i < 4; ++i) {
      l_run[i] = l_run[i] * scl[i] + rs[i];
      m_run[i] = m_new[i];
    }
#pragma unroll
    for (int dt = 0; dt < 8; ++dt)
#pragma unroll
      for (int i = 0; i < 4; ++i) o[dt][i] *= scl[i];

#pragma unroll
    for (int st = 0; st < 4; ++st)
#pragma unroll
      for (int i = 0; i < 4; ++i) {
        const int prow = lh * 4 + i;
        Ps[w * 1024 + prow * 64 + (((st * 2 + (lr >> 3)) ^ (prow & 7)) * 8) + (lr & 7)] =
            f2bf(pv[st][i]);
      }

    short8 pa[2];
#pragma unroll
    for (int s2 = 0; s2 < 2; ++s2)
      pa[s2] = *(const short8*)(Ps + w * 1024 + lr * 64 + (((s2 * 4 + lh) ^ (lr & 7)) * 8));
#pragma unroll
    for (int dt = 0; dt < 8; ++dt) {
#pragma unroll
      for (int s2 = 0; s2 < 2; ++s2) {
        const int row = dt * 16 + lr;
        short8 vb = *(const short8*)((const char*)Vt + row * 128 +
                                     ((s2 * 64 + lh * 16) ^ ((row & 7) << 4)));
        o[dt] = __builtin_amdgcn_mfma_f32_16x16x32_bf16(pa[s2], vb, o[dt], 0, 0, 0);
      }
    }
  }

  float inv[4];
#pragma unroll
  for (int i = 0; i < 4; ++i) inv[i] = 1.f / l_run[i];
  u16* outp = cat + (size_t)(b * 512 + t0 + lh * 4) * 2048 + 1024 + h * 128 + lr;
#pragma unroll
  for (int dt = 0; dt < 8; ++dt)
#pragma unroll
    for (int i = 0; i < 4; ++i)
      outp[(size_t)i * 2048 + dt * 16] = f2bf(o[dt][i] * inv[i]);
}

// ---------------- launcher ----------------
extern "C" void kernel_launch(void* const* d_in, const int* in_sizes, int n_in,
                              void* d_out, int out_size, void* d_ws, size_t ws_size,
                              hipStream_t stream) {
  (void)in_sizes; (void)n_in; (void)out_size; (void)ws_size;
  const float* src      = (const float*)d_in[0];
  const float* tgt      = (const float*)d_in[1];
  const float* src_mask = (const float*)d_in[2];
  const float* tgt_mask = (const float*)d_in[3];
  const float* W_src    = (const float*)d_in[4];
  const float* b_src    = (const float*)d_in[5];
  const float* W_tgt    = (const float*)d_in[6];
  const float* b_tgt    = (const float*)d_in[7];
  const float* W_out    = (const float*)d_in[8];
  const float* b_out    = (const float*)d_in[9];

  char* ws = (char*)d_ws;
  u16* catb = (u16*)(ws);                 // [16384,2048] (src_bf16, then concat[tgt|upd])
  u16* kbuf = (u16*)(ws + 67108864);      // [16384,1024] K
  u16* vTb  = (u16*)(ws + 100663296);     // [256*128,512] V^T
  u16* qbuf = (u16*)(ws + 134217728);     // [16384,1024] Q
  u16* wsrc = (u16*)(ws + 167772160);     // [2048,2048]
  u16* wtgt = (u16*)(ws + 176160768);     // [1024,1024]
  u16* wout = (u16*)(ws + 178257920);     // [1024,2048]

  cvt_f32_bf16<<<2048, 256, 0, stream>>>(src, catb, 16384 * 2048 / 4);
  cvt_f32_bf16<<<1024, 256, 0, stream>>>(W_src, wsrc, 2048 * 2048 / 4);
  cvt_f32_bf16<<<256, 256, 0, stream>>>(W_tgt, wtgt, 1024 * 1024 / 4);
  cvt_f32_bf16<<<512, 256, 0, stream>>>(W_out, wout, 1024 * 2048 / 4);

  // GEMM1: (src @ W_src^T + b_src) * src_mask -> K half to kbuf, V half transposed to vTb
  gemm256<true, true, true><<<512, 512, 0, stream>>>(catb, 2048, wsrc, b_src, src_mask,
                                                     kbuf, 1024, 8, 2048, vTb);

  // tgt -> bf16 into concat buffer first half (src_bf16 now dead)
  cvt_tgt_strided<<<1024, 256, 0, stream>>>(tgt, catb, 16384 * 1024 / 4);

  // GEMM2: q = (tgt @ W_tgt^T + b_tgt) * tgt_mask    [16384,1024]
  gemm256<true, true, false><<<256, 512, 0, stream>>>(catb, 2048, wtgt, b_tgt, tgt_mask,
                                                      qbuf, 1024, 4, 1024, nullptr);

  // attention -> writes upd half of concat buffer
  attn_fwd<<<2048, 256, 0, stream>>>(qbuf, kbuf, vTb, src_mask, catb);

  // GEMM3: out = concat[tgt|upd] @ W_out^T + b_out   [16384,1024] fp32
  gemm256<false, false, false><<<256, 512, 0, stream>>>(catb, 2048, wout, b_out, nullptr,
                                                        (float*)d_out, 1024, 4, 2048, nullptr);
}